// Round 4
// baseline (2446.742 us; speedup 1.0000x reference)
//
#include <hip/hip_runtime.h>
#include <hip/hip_bf16.h>
#include <hip/hip_fp8.h>

// Problem constants
#define B_   4096
#define S_   64
#define D_   9
#define H_   128
#define HZ_  32
#define DT_  0.1f

// f32 region layout (float offsets). Regions overlap in TIME, never within a kernel.
#define OFF_WET    0          // slot hosts WeTm  (bf16, 16384 ush) [encoder only]
#define OFF_VET    16384      // 4096 f32 V_e^T   [encoder only]
#define OFF_WENCT  20480      // slot hosts WencTm (bf16, 81920 ush) [encoder only]
#define OFF_BENC   90624      // 512   [encoder only]
#define OFF_WDT    91136      // slot hosts WdTm (bf16, 32768 ush)
#define OFF_WDECT  123904     // slot hosts WdecTm (bf16, 147456 ush)
#define OFF_BDEC   259584     // 512   (live, decoder)
#define OFF_WOUTT  260096     // 768   (live, decoder)
#define OFF_VDT    260864     // slot hosts VdTm (bf16, 16384 ush) [attnenc MFMA B-frags]
#define OFF_DECD   277248     // dG (524288 ush)
#define OFF_DECC   801536     // 524288 : cG f32
#define F32_TOTAL  1325824
#define PREP_N     277248

typedef __bf16 bf16x8 __attribute__((ext_vector_type(8)));
typedef float  f32x4  __attribute__((ext_vector_type(4)));
typedef float  f32x2  __attribute__((ext_vector_type(2)));

__device__ __forceinline__ float fast_tanh(float x) {
    float e = __expf(2.0f * x);
    return 1.0f - __fdividef(2.0f, e + 1.0f);
}
__device__ __forceinline__ float sigf(float x) {
    return __fdividef(1.0f, 1.0f + __expf(-x));
}
__device__ __forceinline__ float bf_lo(unsigned int u) { return __uint_as_float(u << 16); }
__device__ __forceinline__ float bf_hi(unsigned int u) { return __uint_as_float(u & 0xffff0000u); }
__device__ __forceinline__ float bfu2f(unsigned short u) { return __uint_as_float((unsigned int)u << 16); }
__device__ __forceinline__ unsigned short f2bfu(float f) {
    __hip_bfloat16 b = __float2bfloat16(f);
    return *(unsigned short*)&b;
}
__device__ __forceinline__ unsigned int pack_bf(float lo, float hi) {
    return (unsigned int)f2bfu(lo) | ((unsigned int)f2bfu(hi) << 16);
}
__device__ __forceinline__ float f8tof(unsigned int byte) {
    __hip_fp8_e4m3 t; t.__x = (unsigned char)byte; return (float)t;
}
__device__ __forceinline__ unsigned char f2f8(float f) {
    __hip_fp8_e4m3 q(f); return q.__x;
}
__device__ __forceinline__ unsigned int pack4_f8(float a, float b, float c, float d) {
    return (unsigned int)f2f8(a) | ((unsigned int)f2f8(b) << 8) |
           ((unsigned int)f2f8(c) << 16) | ((unsigned int)f2f8(d) << 24);
}
// native OCP-fp8 pair convert (gfx950): word-select must be a literal -> template param
template<bool HI>
__device__ __forceinline__ f32x2 cvt2f8(unsigned int u) {
    return __builtin_amdgcn_cvt_pk_f32_fp8(u, HI);
}

// ---------------------------------------------------------------- prep (f32 tables)
__global__ void prep_kernel(const float* __restrict__ Wih_e, const float* __restrict__ Whh_e,
    const float* __restrict__ bih_e, const float* __restrict__ bhh_e,
    const float* __restrict__ W_e, const float* __restrict__ V_e,
    const float* __restrict__ W_d, const float* __restrict__ V_d,
    const float* __restrict__ Wih_d, const float* __restrict__ Whh_d,
    const float* __restrict__ bih_d, const float* __restrict__ bhh_d,
    const float* __restrict__ W_out, float* __restrict__ ws) {
  for (int idx = blockIdx.x * blockDim.x + threadIdx.x; idx < PREP_N;
       idx += gridDim.x * blockDim.x) {
    int i = idx;
    if (i < 16384) { continue; }
    i -= 16384;
    if (i < 4096) { int s = i >> 6, t = i & 63; ws[OFF_VET + i] = V_e[t * 64 + s]; continue; }
    i -= 4096;
    if (i < 70144) { continue; }
    i -= 70144;
    if (i < 512) { ws[OFF_BENC + i] = bih_e[i] + bhh_e[i]; continue; }
    i -= 512;
    if (i < 32768) { continue; }
    i -= 32768;
    if (i < 135680) { continue; }
    i -= 135680;
    if (i < 512) { ws[OFF_BDEC + i] = bih_d[i] + bhh_d[i]; continue; }
    i -= 512;
    if (i < 768) { int k = i / 3, j = i % 3; ws[OFF_WOUTT + i] = W_out[j * 256 + k]; continue; }
  }
}

// ---------------------------------------------------------------- prep decoder MFMA weights
__global__ void prep_mfma_kernel(const float* __restrict__ W_d,
    const float* __restrict__ Wih_d, const float* __restrict__ Whh_d,
    unsigned short* __restrict__ WdTm, unsigned short* __restrict__ WdecTm) {
  int idx = blockIdx.x * blockDim.x + threadIdx.x;
  if (idx < 32768) {
    int j = idx & 7, l = (idx >> 3) & 63, t = idx >> 9;
    int nt = t & 7, ks = t >> 3;
    int k = ks * 32 + (l >> 4) * 8 + j;
    int n = nt * 16 + (l & 15);
    WdTm[idx] = f2bfu(W_d[n * 256 + k]);
    return;
  }
  int i2 = idx - 32768;
  if (i2 < 147456) {
    int j = i2 & 7, l = (i2 >> 3) & 63, t = i2 >> 9;
    int ks = t % 9, tile = t / 9;
    int q = tile & 3, is = tile >> 2;
    int k = ks * 32 + (l >> 4) * 8 + j;
    int g = q * 128 + is * 16 + (l & 15);
    float v;
    if (k < 128)      v = Whh_d[g * 128 + k];
    else if (k < 256) v = Wih_d[g * 137 + 9 + (k - 128)];
    else if (k < 265) v = Wih_d[g * 137 + (k - 256)];
    else              v = 0.f;
    WdecTm[i2] = f2bfu(v);
  }
}

// ---------------------------------------------------------------- prep encoder MFMA weights + VdTm
__global__ void prep_enc_mfma_kernel(const float* __restrict__ W_e,
    const float* __restrict__ Wih_e, const float* __restrict__ Whh_e,
    const float* __restrict__ V_d,
    unsigned short* __restrict__ WeTm, unsigned short* __restrict__ WencTm,
    unsigned short* __restrict__ VdTm) {
  int idx = blockIdx.x * blockDim.x + threadIdx.x;
  if (idx < 16384) {
    int j = idx & 7, l = (idx >> 3) & 63, tile = idx >> 9;
    int nt = tile & 3, ks = tile >> 2;
    int k = ks * 32 + (l >> 4) * 8 + j;
    int n = nt * 16 + (l & 15);
    WeTm[idx] = f2bfu(W_e[n * 256 + k]);
    return;
  }
  int i2 = idx - 16384;
  if (i2 < 81920) {
    int j = i2 & 7, l = (i2 >> 3) & 63, tile = i2 >> 9;
    int ks = tile % 5, tq = tile / 5;
    int q = tq & 3, is = tq >> 2;
    int kk = (l >> 4) * 8 + j;
    int g = q * 128 + is * 16 + (l & 15);
    float v;
    if (ks < 4) v = Whh_e[g * 128 + ks * 32 + kk];
    else        v = (kk < 9) ? Wih_e[g * 9 + kk] : 0.f;
    WencTm[i2] = f2bfu(v);
    return;
  }
  int i3 = i2 - 81920;
  if (i3 < 16384) {
    int j = i3 & 7, l = (i3 >> 3) & 63, tile = i3 >> 9;
    int nt = tile & 7, ks = tile >> 3;
    int i = ks * 32 + (l >> 4) * 8 + j;
    int n = nt * 16 + (l & 15);
    VdTm[i3] = f2bfu(V_d[n * 128 + i]);
  }
}

// ---------------------------------------------------------------- encoder (MFMA, 16 batches, 512 thr)
__global__ __launch_bounds__(512, 1) void encoder_mfma_kernel(
    const float* __restrict__ x_in, const float* __restrict__ ws,
    const float* __restrict__ v_e_g,
    const unsigned short* __restrict__ WeTm, const unsigned short* __restrict__ WencTm,
    __hip_bfloat16* __restrict__ EH,
    unsigned short* __restrict__ dG, float* __restrict__ cG) {
  __shared__ unsigned short hA[2][16 * 296];  // [h | c | xs | zeros]
  __shared__ float cF[16 * 132];
  __shared__ float ahL[16 * 64];
  __shared__ unsigned short aiL[16 * 576];    // bf16
  __shared__ unsigned short xbL[16 * 576];    // bf16

  const int tid = threadIdx.x;
  const int b0 = blockIdx.x * 16;
  const int l = tid & 63, w = tid >> 6;
  const int quad = l >> 4, l15 = l & 15;

  for (int i = tid; i < 16 * 576; i += 512) {
    int m = i / 576, r = i % 576;
    xbL[i] = f2bfu(x_in[(size_t)(b0 + m) * 576 + r]);
  }
  for (int i = tid; i < 2 * 16 * 296; i += 512) ((unsigned short*)hA)[i] = 0;
  for (int i = tid; i < 16 * 132; i += 512) cF[i] = 0.f;
  __syncthreads();

  {
    const float* __restrict__ VeT = ws + OFF_VET;
    for (int i = tid; i < 16 * 576; i += 512) {
      int t = i & 63, dd = (i >> 6) % 9, m = i / 576;
      float acc = 0.f;
      for (int s = 0; s < 64; ++s) acc += bfu2f(xbL[m * 576 + s * 9 + dd]) * VeT[s * 64 + t];
      aiL[m * 576 + dd * 64 + t] = f2bfu(acc);
    }
  }
  const float ve_r = v_e_g[l];
  const int ig = w * 16 + l15;
  float bbq[4];
  #pragma unroll
  for (int q = 0; q < 4; ++q) bbq[q] = ws[OFF_BENC + q * 128 + ig];
  __syncthreads();

  for (int t = 0; t < S_; ++t) {
    unsigned short* bufC = hA[t & 1];
    unsigned short* bufN = hA[(t + 1) & 1];
    if (w < 4) {
      f32x4 acc = {0.f, 0.f, 0.f, 0.f};
      #pragma unroll
      for (int ks = 0; ks < 8; ++ks) {
        uint4 au = *(const uint4*)&bufC[l15 * 296 + ks * 32 + quad * 8];
        uint4 bu = *(const uint4*)(WeTm + (size_t)((ks * 4 + w) * 64 + l) * 8);
        acc = __builtin_amdgcn_mfma_f32_16x16x32_bf16(
            __builtin_bit_cast(bf16x8, au), __builtin_bit_cast(bf16x8, bu), acc, 0, 0, 0);
      }
      #pragma unroll
      for (int r = 0; r < 4; ++r)
        ahL[(quad * 4 + r) * 64 + w * 16 + l15] = acc[r];
    }
    __syncthreads();
    {
      const int m0 = 2 * w, m1 = 2 * w + 1;
      float a0 = ahL[m0 * 64 + l], a1 = ahL[m1 * 64 + l];
      float e0k = -1e30f, e1k = -1e30f;
      #pragma unroll
      for (int dd = 0; dd < 9; ++dd) {
        float t0 = fast_tanh(a0 + bfu2f(aiL[m0 * 576 + dd * 64 + l])) * ve_r;
        float t1 = fast_tanh(a1 + bfu2f(aiL[m1 * 576 + dd * 64 + l])) * ve_r;
        #pragma unroll
        for (int off = 32; off; off >>= 1) {
          t0 += __shfl_xor(t0, off, 64);
          t1 += __shfl_xor(t1, off, 64);
        }
        if (l == dd) { e0k = t0; e1k = t1; }
      }
      float mx0 = e0k, mx1 = e1k;
      #pragma unroll
      for (int off = 8; off; off >>= 1) {
        mx0 = fmaxf(mx0, __shfl_xor(mx0, off, 64));
        mx1 = fmaxf(mx1, __shfl_xor(mx1, off, 64));
      }
      float ex0 = (l < 9) ? __expf(e0k - mx0) : 0.f;
      float ex1 = (l < 9) ? __expf(e1k - mx1) : 0.f;
      float s0 = ex0, s1 = ex1;
      #pragma unroll
      for (int off = 8; off; off >>= 1) {
        s0 += __shfl_xor(s0, off, 64);
        s1 += __shfl_xor(s1, off, 64);
      }
      if (l < 9) {
        bufC[m0 * 296 + 256 + l] = f2bfu(__fdividef(ex0, s0) * bfu2f(xbL[m0 * 576 + t * 9 + l]));
        bufC[m1 * 296 + 256 + l] = f2bfu(__fdividef(ex1, s1) * bfu2f(xbL[m1 * 576 + t * 9 + l]));
      }
    }
    __syncthreads();
    {
      uint4 af[5];
      #pragma unroll
      for (int ks = 0; ks < 4; ++ks)
        af[ks] = *(const uint4*)&bufC[l15 * 296 + ks * 32 + quad * 8];
      af[4] = *(const uint4*)&bufC[l15 * 296 + 256 + quad * 8];
      f32x4 g4[4];
      #pragma unroll
      for (int q = 0; q < 4; ++q) {
        f32x4 acc = {0.f, 0.f, 0.f, 0.f};
        #pragma unroll
        for (int ks = 0; ks < 5; ++ks) {
          uint4 bu = *(const uint4*)(WencTm + (size_t)(((w * 4 + q) * 5 + ks) * 64 + l) * 8);
          acc = __builtin_amdgcn_mfma_f32_16x16x32_bf16(
              __builtin_bit_cast(bf16x8, af[ks]), __builtin_bit_cast(bf16x8, bu), acc, 0, 0, 0);
        }
        g4[q] = acc;
      }
      #pragma unroll
      for (int r = 0; r < 4; ++r) {
        int m = quad * 4 + r;
        float gi = g4[0][r] + bbq[0];
        float gf = g4[1][r] + bbq[1];
        float gg = g4[2][r] + bbq[2];
        float go = g4[3][r] + bbq[3];
        float co = cF[m * 132 + ig];
        float cn = sigf(gf) * co + sigf(gi) * fast_tanh(gg);
        float hn = sigf(go) * fast_tanh(cn);
        cF[m * 132 + ig] = cn;
        bufN[m * 296 + ig] = f2bfu(hn);
        bufN[m * 296 + 128 + ig] = f2bfu(cn);
        EH[((size_t)(b0 + m) * S_ + t) * H_ + ig] = __float2bfloat16(hn);
      }
    }
    __syncthreads();
  }
  for (int i = tid; i < 16 * 128; i += 512) {
    int m = i >> 7, ii = i & 127;
    dG[(size_t)(b0 + m) * 128 + ii] = hA[0][m * 296 + ii];
    cG[(size_t)(b0 + m) * 128 + ii] = cF[m * 132 + ii];
  }
}

// ---------------------------------------------------------------- attn_encoder^T via MFMA -> fp8
__global__ __launch_bounds__(256) void attnenc_mfma_kernel(
    const unsigned short* __restrict__ EH, const unsigned short* __restrict__ VdTm,
    unsigned char* __restrict__ AETf8, unsigned char* __restrict__ EHf8) {
  const int tid = threadIdx.x;
  const int b = blockIdx.x * 4 + (tid >> 6);
  const int l = tid & 63;
  const int quad = l >> 4, l15 = l & 15;

  const unsigned short* ehb = EH + (size_t)b * 8192;
  uint4 A[4][4];
  #pragma unroll
  for (int st = 0; st < 4; ++st)
    #pragma unroll
    for (int ks = 0; ks < 4; ++ks)
      A[st][ks] = *(const uint4*)(ehb + (st * 16 + l15) * 128 + ks * 32 + quad * 8);

  {
    unsigned char* e8b = EHf8 + (size_t)b * 8192;
    #pragma unroll
    for (int st = 0; st < 4; ++st)
      #pragma unroll
      for (int ks = 0; ks < 4; ++ks) {
        uint4 a = A[st][ks];
        uint2 pk;
        pk.x = pack4_f8(bf_lo(a.x), bf_hi(a.x), bf_lo(a.y), bf_hi(a.y));
        pk.y = pack4_f8(bf_lo(a.z), bf_hi(a.z), bf_lo(a.w), bf_hi(a.w));
        *(uint2*)(e8b + (st * 16 + l15) * 128 + ks * 32 + quad * 8) = pk;
      }
  }

  unsigned char* outb = AETf8 + (size_t)b * 8192;
  const int k = l15;
  #pragma unroll
  for (int nt = 0; nt < 8; ++nt) {
    uint4 Bf[4];
    #pragma unroll
    for (int ks = 0; ks < 4; ++ks)
      Bf[ks] = *(const uint4*)(VdTm + (size_t)((ks * 8 + nt) * 64 + l) * 8);
    int kg = nt * 16 + k;
    int kb = kg >> 3, k7 = kg & 7;
    #pragma unroll
    for (int st = 0; st < 4; ++st) {
      f32x4 acc = {0.f, 0.f, 0.f, 0.f};
      #pragma unroll
      for (int ks = 0; ks < 4; ++ks)
        acc = __builtin_amdgcn_mfma_f32_16x16x32_bf16(
            __builtin_bit_cast(bf16x8, A[st][ks]), __builtin_bit_cast(bf16x8, Bf[ks]), acc, 0, 0, 0);
      #pragma unroll
      for (int r = 0; r < 4; ++r) {
        int s = st * 16 + quad * 4 + r;
        outb[kb * 512 + s * 8 + k7] = f2f8(acc[r]);
      }
    }
  }
}

// ---------------------------------------------------------------- fused persistent decoder v3
// 256 blocks x 512 threads (1/CU, 8 waves), 16 batches/block.
// Gates weights (WdecTm) in registers (144 VGPR) -- pressure elsewhere reduced so
// they actually stay resident: ks-outer MFMA loop (af03 preload = 16 VGPR instead
// of 36), native fp8 pk-converts, 4 barriers/step.
__global__ __launch_bounds__(512, 2) void dec_fused_kernel(
    const float* __restrict__ ws,
    const unsigned char* __restrict__ AETf8, const unsigned char* __restrict__ EHf8,
    const unsigned short* __restrict__ dG, const float* __restrict__ cG,
    const unsigned short* __restrict__ WdTm, const unsigned short* __restrict__ WdecTm,
    const float* __restrict__ v_d_g, const float* __restrict__ b_out_g,
    const float* __restrict__ smean_g, const float* __restrict__ sstd_g,
    const float* __restrict__ pmean_g,
    const float* __restrict__ x_in,
    float* __restrict__ out) {
  __shared__ unsigned char  AET[16][8192];   // 131072 B : staged AETf8 (kb*512 + s*8 + k7)
  __shared__ unsigned short gA[16 * 296];    //   9472 B : gates A  [d(128)|ctx(128)|phys(9)|0]
  __shared__ unsigned short dcB[16 * 264];   //   8448 B : ad-GEMM A [h(128)|c(128)]
  __shared__ unsigned short adL[16 * 128];   //   4096 B : attn-hidden ad (bf16)
  __shared__ float          bet[16][64];     //   4096 B : beta
  __shared__ float          vdL[128];        //    512 B
  __shared__ float          pcs[16 * 3 * 8]; //   1536 B : pred partials
  __shared__ float          pvs[16 * 12];    //    768 B : pos/vel/acc
  // total 160,000 B -> 1 block/CU (8 waves)

  const int tid = threadIdx.x;
  const int b0 = blockIdx.x * 16;
  const int l = tid & 63, w = tid >> 6;      // 8 waves
  const int quad = l >> 4, l15 = l & 15;
  const int i = w * 16 + l15;                // this thread's output column (0..127)

  // ---- preload gates B-fragments into registers (once)
  uint4 wFrag[4][9];
  #pragma unroll
  for (int q = 0; q < 4; ++q)
    #pragma unroll
    for (int ks = 0; ks < 9; ++ks)
      wFrag[q][ks] = *(const uint4*)(WdecTm + (size_t)(((w * 4 + q) * 9 + ks) * 64 + l) * 8);

  // ---- one-time init: zero gA (pad cols must be non-NaN), stage AET, vdL
  for (int idx = tid; idx < 16 * 296; idx += 512) gA[idx] = 0;
  {
    const uint4* src = (const uint4*)(AETf8 + (size_t)b0 * 8192);
    uint4* dst = (uint4*)AET;
    for (int idx = tid; idx < 8192; idx += 512) dst[idx] = src[idx];
  }
  if (tid < 128) vdL[tid] = v_d_g[tid];
  __syncthreads();

  // ---- load encoder final state into gA.d / dcB; phys init
  if (tid < 256) {
    int m = tid >> 4, i0 = (tid & 15) * 8;
    uint4 dv = *(const uint4*)(dG + (size_t)(b0 + m) * 128 + i0);
    *(uint4*)&gA[m * 296 + i0] = dv;
    *(uint4*)&dcB[m * 264 + i0] = dv;
    float4 c0 = *(const float4*)(cG + (size_t)(b0 + m) * 128 + i0);
    float4 c1 = *(const float4*)(cG + (size_t)(b0 + m) * 128 + i0 + 4);
    uint4 pk;
    pk.x = pack_bf(c0.x, c0.y); pk.y = pack_bf(c0.z, c0.w);
    pk.z = pack_bf(c1.x, c1.y); pk.w = pack_bf(c1.z, c1.w);
    *(uint4*)&dcB[m * 264 + 128 + i0] = pk;
  }
  if (tid < 48) {
    int m = tid / 3, jj = tid % 3;
    const float* xi = x_in + (size_t)(b0 + m) * 576;
    float sm = smean_g[jj], ss = sstd_g[jj], pm = pmean_g[jj];
    float v  = xi[63 * 9 + 3 + jj] * ss + sm;
    float pv = xi[62 * 9 + 3 + jj] * ss + sm;
    float pos = xi[63 * 9 + jj] + pm;
    float ac = (v - pv) / DT_;
    float* P = pvs + m * 12;
    P[jj] = pos; P[3 + jj] = v; P[6 + jj] = ac;
    gA[m * 296 + 256 + jj]     = f2bfu(pos - pm);
    gA[m * 296 + 256 + 3 + jj] = f2bfu((v - sm) / ss);
    gA[m * 296 + 256 + 6 + jj] = f2bfu(ac / ss);
  }
  // per-thread constants
  float bb[4];
  #pragma unroll
  for (int q = 0; q < 4; ++q) bb[q] = ws[OFF_BDEC + q * 128 + i];
  float k_sm = 0.f, k_ss = 1.f, k_pm = 0.f, k_bo = 0.f;
  if (tid < 48) {
    int jj = tid % 3;
    k_sm = smean_g[jj]; k_ss = sstd_g[jj]; k_pm = pmean_g[jj]; k_bo = b_out_g[jj];
  }
  // c-state in registers: this thread owns rows m=quad*4+r at column i
  float cReg[4];
  #pragma unroll
  for (int r = 0; r < 4; ++r)
    cReg[r] = cG[(size_t)(b0 + quad * 4 + r) * 128 + i];
  __syncthreads();

  // ---- initial ad = [d|c] @ W_d^T
  {
    const int nt = w;
    f32x4 acc = {0.f, 0.f, 0.f, 0.f};
    #pragma unroll
    for (int ks = 0; ks < 8; ++ks) {
      uint4 au = *(const uint4*)&dcB[l15 * 264 + ks * 32 + quad * 8];
      uint4 bu = *(const uint4*)(WdTm + (size_t)((ks * 8 + nt) * 64 + l) * 8);
      acc = __builtin_amdgcn_mfma_f32_16x16x32_bf16(
          __builtin_bit_cast(bf16x8, au), __builtin_bit_cast(bf16x8, bu), acc, 0, 0, 0);
    }
    int n = nt * 16 + l15;
    #pragma unroll
    for (int r = 0; r < 4; ++r) adL[(quad * 4 + r) * 128 + n] = f2bfu(acc[r]);
  }
  __syncthreads();

  // ---- 32 decoder steps, fully in-kernel
  for (int hz = 0; hz < HZ_; ++hz) {
    // A: scores. wave w handles batches 2w, 2w+1; lane = s; full k=128.
    {
      const int m0 = 2 * w, m1 = 2 * w + 1;
      const unsigned char* a0p = AET[m0];
      const unsigned char* a1p = AET[m1];
      float e0 = 0.f, e1 = 0.f;
      #pragma unroll
      for (int kb = 0; kb < 16; ++kb) {
        uint2 av0 = *(const uint2*)(a0p + kb * 512 + l * 8);
        uint2 av1 = *(const uint2*)(a1p + kb * 512 + l * 8);
        uint4 ad0 = *(const uint4*)(adL + m0 * 128 + kb * 8);
        uint4 ad1 = *(const uint4*)(adL + m1 * 128 + kb * 8);
        float4 v0 = *(const float4*)&vdL[kb * 8];
        float4 v1 = *(const float4*)&vdL[kb * 8 + 4];
        f32x2 p0 = cvt2f8<false>(av0.x), p1 = cvt2f8<true>(av0.x);
        f32x2 p2 = cvt2f8<false>(av0.y), p3 = cvt2f8<true>(av0.y);
        e0 += fast_tanh(bf_lo(ad0.x) + p0[0]) * v0.x;
        e0 += fast_tanh(bf_hi(ad0.x) + p0[1]) * v0.y;
        e0 += fast_tanh(bf_lo(ad0.y) + p1[0]) * v0.z;
        e0 += fast_tanh(bf_hi(ad0.y) + p1[1]) * v0.w;
        e0 += fast_tanh(bf_lo(ad0.z) + p2[0]) * v1.x;
        e0 += fast_tanh(bf_hi(ad0.z) + p2[1]) * v1.y;
        e0 += fast_tanh(bf_lo(ad0.w) + p3[0]) * v1.z;
        e0 += fast_tanh(bf_hi(ad0.w) + p3[1]) * v1.w;
        f32x2 r0 = cvt2f8<false>(av1.x), r1 = cvt2f8<true>(av1.x);
        f32x2 r2 = cvt2f8<false>(av1.y), r3 = cvt2f8<true>(av1.y);
        e1 += fast_tanh(bf_lo(ad1.x) + r0[0]) * v0.x;
        e1 += fast_tanh(bf_hi(ad1.x) + r0[1]) * v0.y;
        e1 += fast_tanh(bf_lo(ad1.y) + r1[0]) * v0.z;
        e1 += fast_tanh(bf_hi(ad1.y) + r1[1]) * v0.w;
        e1 += fast_tanh(bf_lo(ad1.z) + r2[0]) * v1.x;
        e1 += fast_tanh(bf_hi(ad1.z) + r2[1]) * v1.y;
        e1 += fast_tanh(bf_lo(ad1.w) + r3[0]) * v1.z;
        e1 += fast_tanh(bf_hi(ad1.w) + r3[1]) * v1.w;
      }
      float mx0 = e0, mx1 = e1;
      #pragma unroll
      for (int off = 32; off; off >>= 1) {
        mx0 = fmaxf(mx0, __shfl_xor(mx0, off, 64));
        mx1 = fmaxf(mx1, __shfl_xor(mx1, off, 64));
      }
      float ex0 = __expf(e0 - mx0), ex1 = __expf(e1 - mx1);
      float s0 = ex0, s1 = ex1;
      #pragma unroll
      for (int off = 32; off; off >>= 1) {
        s0 += __shfl_xor(s0, off, 64);
        s1 += __shfl_xor(s1, off, 64);
      }
      bet[m0][l] = __fdividef(ex0, s0);
      bet[m1][l] = __fdividef(ex1, s1);
    }
    // C: context = beta @ EH (fp8 stream, same-wave bet -> no barrier needed)
    #pragma unroll
    for (int mb = 0; mb < 2; ++mb) {
      const int m = 2 * w + mb;
      const unsigned char* ehb = EHf8 + (size_t)(b0 + m) * 8192;
      const int i0 = l15 * 8;
      float a[8];
      #pragma unroll
      for (int r = 0; r < 8; ++r) a[r] = 0.f;
      #pragma unroll
      for (int it = 0; it < 16; ++it) {
        int s = quad * 16 + it;
        uint2 ev = *(const uint2*)(ehb + s * 128 + i0);
        float bt = bet[m][s];
        f32x2 c0 = cvt2f8<false>(ev.x), c1 = cvt2f8<true>(ev.x);
        f32x2 c2 = cvt2f8<false>(ev.y), c3 = cvt2f8<true>(ev.y);
        a[0] += bt * c0[0]; a[1] += bt * c0[1];
        a[2] += bt * c1[0]; a[3] += bt * c1[1];
        a[4] += bt * c2[0]; a[5] += bt * c2[1];
        a[6] += bt * c3[0]; a[7] += bt * c3[1];
      }
      #pragma unroll
      for (int r = 0; r < 8; ++r) {
        a[r] += __shfl_xor(a[r], 16, 64);
        a[r] += __shfl_xor(a[r], 32, 64);
      }
      if (quad == 0) {
        uint4 pk;
        pk.x = pack_bf(a[0], a[1]); pk.y = pack_bf(a[2], a[3]);
        pk.z = pack_bf(a[4], a[5]); pk.w = pack_bf(a[6], a[7]);
        *(uint4*)&gA[m * 296 + 128 + i0] = pk;
      }
    }
    __syncthreads();

    // E: preload ONLY the d-region A-frags (ks 0..3) -- these race with G's h-write.
    // ctx (ks 4..7) and phys (ks 8) are stable during G and read in-loop.
    uint4 af03[4];
    #pragma unroll
    for (int ks = 0; ks < 4; ++ks)
      af03[ks] = *(const uint4*)&gA[l15 * 296 + ks * 32 + quad * 8];
    __syncthreads();

    // G: gates MFMA, ks-outer / q-inner (B from registers); LSTM update (c in regs)
    {
      f32x4 g4[4];
      #pragma unroll
      for (int q = 0; q < 4; ++q) g4[q] = (f32x4){0.f, 0.f, 0.f, 0.f};
      #pragma unroll
      for (int ks = 0; ks < 4; ++ks) {
        #pragma unroll
        for (int q = 0; q < 4; ++q)
          g4[q] = __builtin_amdgcn_mfma_f32_16x16x32_bf16(
              __builtin_bit_cast(bf16x8, af03[ks]), __builtin_bit_cast(bf16x8, wFrag[q][ks]),
              g4[q], 0, 0, 0);
      }
      #pragma unroll
      for (int ks = 4; ks < 9; ++ks) {
        uint4 af = *(const uint4*)&gA[l15 * 296 + ks * 32 + quad * 8];
        #pragma unroll
        for (int q = 0; q < 4; ++q)
          g4[q] = __builtin_amdgcn_mfma_f32_16x16x32_bf16(
              __builtin_bit_cast(bf16x8, af), __builtin_bit_cast(bf16x8, wFrag[q][ks]),
              g4[q], 0, 0, 0);
      }
      #pragma unroll
      for (int r = 0; r < 4; ++r) {
        int m = quad * 4 + r;
        float gi = g4[0][r] + bb[0];
        float gf = g4[1][r] + bb[1];
        float gg = g4[2][r] + bb[2];
        float go = g4[3][r] + bb[3];
        float cn = sigf(gf) * cReg[r] + sigf(gi) * fast_tanh(gg);
        float hn = sigf(go) * fast_tanh(cn);
        cReg[r] = cn;
        unsigned short hb = f2bfu(hn);
        gA[m * 296 + i] = hb;
        dcB[m * 264 + i] = hb;
        dcB[m * 264 + 128 + i] = f2bfu(cn);
      }
    }
    __syncthreads();

    // I: next ad = [h|c] @ W_d^T (WdTm streamed from L2, 64 KB/block-step)
    {
      const int nt = w;
      f32x4 acc = {0.f, 0.f, 0.f, 0.f};
      #pragma unroll
      for (int ks = 0; ks < 8; ++ks) {
        uint4 au = *(const uint4*)&dcB[l15 * 264 + ks * 32 + quad * 8];
        uint4 bu = *(const uint4*)(WdTm + (size_t)((ks * 8 + nt) * 64 + l) * 8);
        acc = __builtin_amdgcn_mfma_f32_16x16x32_bf16(
            __builtin_bit_cast(bf16x8, au), __builtin_bit_cast(bf16x8, bu), acc, 0, 0, 0);
      }
      int n = nt * 16 + l15;
      #pragma unroll
      for (int r = 0; r < 4; ++r) adL[(quad * 4 + r) * 128 + n] = f2bfu(acc[r]);
    }
    // out-projection partials over [d_new | ctx] (reads gA, no conflict with I)
    if (tid < 384) {
      int m = tid / 24, r2 = tid % 24, jj = r2 >> 3, part = r2 & 7;
      float acc = 0.f;
      #pragma unroll 4
      for (int k = part * 32; k < part * 32 + 32; ++k)
        acc += bfu2f(gA[m * 296 + k]) * ws[OFF_WOUTT + k * 3 + jj];
      pcs[(m * 3 + jj) * 8 + part] = acc;
    }
    __syncthreads();

    // K: final pred + Verlet + output + next phys into gA.
    // No trailing barrier: K's writes (gA.phys, pvs) are disjoint from the next
    // step's scores/C phases and ordered before all E-reads by the C barrier.
    if (tid < 48) {
      int m = tid / 3, jj = tid % 3;
      float s = k_bo;
      #pragma unroll
      for (int p = 0; p < 8; ++p) s += pcs[(m * 3 + jj) * 8 + p];
      float pacc = s * k_ss;
      float* P = pvs + m * 12;
      float pos = P[jj], vel = P[3 + jj], ac = P[6 + jj];
      float ppred = pos + vel * DT_ + 0.5f * ac * DT_ * DT_;
      float vnew  = vel + 0.5f * (ac + pacc) * DT_;
      size_t ob = ((size_t)(b0 + m) * HZ_ + hz) * 9;
      out[ob + jj] = ppred; out[ob + 3 + jj] = vnew; out[ob + 6 + jj] = pacc;
      P[jj] = ppred; P[3 + jj] = vnew; P[6 + jj] = pacc;
      gA[m * 296 + 256 + jj]     = f2bfu(ppred - k_pm);
      gA[m * 296 + 256 + 3 + jj] = f2bfu((vnew - k_sm) / k_ss);
      gA[m * 296 + 256 + 6 + jj] = f2bfu(pacc / k_ss);
    }
  }
}

// ---------------------------------------------------------------- launch
extern "C" void kernel_launch(void* const* d_in, const int* in_sizes, int n_in,
                              void* d_out, int out_size, void* d_ws, size_t ws_size,
                              hipStream_t stream) {
  (void)in_sizes; (void)n_in; (void)out_size; (void)ws_size;
  const float* x      = (const float*)d_in[0];
  const float* Wih_e  = (const float*)d_in[1];
  const float* Whh_e  = (const float*)d_in[2];
  const float* bih_e  = (const float*)d_in[3];
  const float* bhh_e  = (const float*)d_in[4];
  const float* W_e    = (const float*)d_in[5];
  const float* V_e    = (const float*)d_in[6];
  const float* v_e    = (const float*)d_in[7];
  const float* W_d    = (const float*)d_in[8];
  const float* V_d    = (const float*)d_in[9];
  const float* v_d    = (const float*)d_in[10];
  const float* Wih_d  = (const float*)d_in[11];
  const float* Whh_d  = (const float*)d_in[12];
  const float* bih_d  = (const float*)d_in[13];
  const float* bhh_d  = (const float*)d_in[14];
  const float* W_out  = (const float*)d_in[15];
  const float* b_out  = (const float*)d_in[16];
  const float* smean  = (const float*)d_in[17];
  const float* sstd   = (const float*)d_in[18];
  const float* pmean  = (const float*)d_in[19];

  float* ws = (float*)d_ws;
  unsigned short* WeTm   = (unsigned short*)(ws + OFF_WET);
  unsigned short* WencTm = (unsigned short*)(ws + OFF_WENCT);
  unsigned short* WdTm   = (unsigned short*)(ws + OFF_WDT);
  unsigned short* WdecTm = (unsigned short*)(ws + OFF_WDECT);
  unsigned short* VdTm   = (unsigned short*)(ws + OFF_VDT);
  unsigned short* dG     = (unsigned short*)(ws + OFF_DECD);
  float* cG = ws + OFF_DECC;
  unsigned short* ub  = (unsigned short*)(ws + F32_TOTAL);
  unsigned short* EH  = ub;
  unsigned char*  AETf8 = (unsigned char*)(ub + 33554432);     // 33.5 MB
  unsigned char*  EHf8  = AETf8 + (size_t)B_ * 8192;           // 33.5 MB
  float* out = (float*)d_out;

  prep_kernel<<<(PREP_N + 255) / 256, 256, 0, stream>>>(
      Wih_e, Whh_e, bih_e, bhh_e, W_e, V_e, W_d, V_d,
      Wih_d, Whh_d, bih_d, bhh_d, W_out, ws);
  prep_mfma_kernel<<<(32768 + 147456 + 255) / 256, 256, 0, stream>>>(
      W_d, Wih_d, Whh_d, WdTm, WdecTm);
  prep_enc_mfma_kernel<<<(16384 + 81920 + 16384 + 255) / 256, 256, 0, stream>>>(
      W_e, Wih_e, Whh_e, V_d, WeTm, WencTm, VdTm);
  encoder_mfma_kernel<<<B_ / 16, 512, 0, stream>>>(
      x, ws, v_e, WeTm, WencTm, (__hip_bfloat16*)EH, dG, cG);
  attnenc_mfma_kernel<<<B_ / 4, 256, 0, stream>>>(EH, VdTm, AETf8, EHf8);
  dec_fused_kernel<<<B_ / 16, 512, 0, stream>>>(
      ws, AETf8, EHf8, dG, cG, WdTm, WdecTm,
      v_d, b_out, smean, sstd, pmean, x, out);
}

// Round 5
// 2001.946 us; speedup vs baseline: 1.2222x; 1.2222x over previous
//
#include <hip/hip_runtime.h>
#include <hip/hip_bf16.h>
#include <hip/hip_fp8.h>

// Problem constants
#define B_   4096
#define S_   64
#define D_   9
#define H_   128
#define HZ_  32
#define DT_  0.1f

// f32 region layout (float offsets). Regions overlap in TIME, never within a kernel.
#define OFF_WET    0          // slot hosts WeTm  (bf16, 16384 ush) [encoder only]
#define OFF_VET    16384      // 4096 f32 V_e^T   [encoder only]
#define OFF_WENCT  20480      // slot hosts WencTm (bf16, 81920 ush) [encoder only]
#define OFF_BENC   90624      // 512   [encoder only]
#define OFF_WDT    91136      // slot hosts WdTm (bf16, 32768 ush)
#define OFF_WDECT  123904     // slot hosts WdecTm (bf16, 147456 ush)
#define OFF_BDEC   259584     // 512   (live, decoder)
#define OFF_WOUTT  260096     // 768   (live, decoder)
#define OFF_VDT    260864     // slot hosts VdTm (bf16, 16384 ush) [attnenc MFMA B-frags]
#define OFF_DECD   277248     // dG (524288 ush)
#define OFF_DECC   801536     // 524288 : cG f32
#define F32_TOTAL  1325824
#define PREP_N     277248

typedef __bf16 bf16x8 __attribute__((ext_vector_type(8)));
typedef float  f32x4  __attribute__((ext_vector_type(4)));
typedef float  f32x2  __attribute__((ext_vector_type(2)));

__device__ __forceinline__ float fast_tanh(float x) {
    float e = __expf(2.0f * x);
    return 1.0f - __fdividef(2.0f, e + 1.0f);
}
__device__ __forceinline__ float sigf(float x) {
    return __fdividef(1.0f, 1.0f + __expf(-x));
}
__device__ __forceinline__ float bf_lo(unsigned int u) { return __uint_as_float(u << 16); }
__device__ __forceinline__ float bf_hi(unsigned int u) { return __uint_as_float(u & 0xffff0000u); }
__device__ __forceinline__ float bfu2f(unsigned short u) { return __uint_as_float((unsigned int)u << 16); }
__device__ __forceinline__ unsigned short f2bfu(float f) {
    __hip_bfloat16 b = __float2bfloat16(f);
    return *(unsigned short*)&b;
}
__device__ __forceinline__ unsigned int pack_bf(float lo, float hi) {
    return (unsigned int)f2bfu(lo) | ((unsigned int)f2bfu(hi) << 16);
}
__device__ __forceinline__ float f8tof(unsigned int byte) {
    __hip_fp8_e4m3 t; t.__x = (unsigned char)byte; return (float)t;
}
__device__ __forceinline__ unsigned char f2f8(float f) {
    __hip_fp8_e4m3 q(f); return q.__x;
}
__device__ __forceinline__ unsigned int pack4_f8(float a, float b, float c, float d) {
    return (unsigned int)f2f8(a) | ((unsigned int)f2f8(b) << 8) |
           ((unsigned int)f2f8(c) << 16) | ((unsigned int)f2f8(d) << 24);
}
// native OCP-fp8 pair convert (gfx950): word-select must be a literal -> template param
template<bool HI>
__device__ __forceinline__ f32x2 cvt2f8(unsigned int u) {
    return __builtin_amdgcn_cvt_pk_f32_fp8(u, HI);
}

// ---------------------------------------------------------------- prep (f32 tables)
__global__ void prep_kernel(const float* __restrict__ Wih_e, const float* __restrict__ Whh_e,
    const float* __restrict__ bih_e, const float* __restrict__ bhh_e,
    const float* __restrict__ W_e, const float* __restrict__ V_e,
    const float* __restrict__ W_d, const float* __restrict__ V_d,
    const float* __restrict__ Wih_d, const float* __restrict__ Whh_d,
    const float* __restrict__ bih_d, const float* __restrict__ bhh_d,
    const float* __restrict__ W_out, float* __restrict__ ws) {
  for (int idx = blockIdx.x * blockDim.x + threadIdx.x; idx < PREP_N;
       idx += gridDim.x * blockDim.x) {
    int i = idx;
    if (i < 16384) { continue; }
    i -= 16384;
    if (i < 4096) { int s = i >> 6, t = i & 63; ws[OFF_VET + i] = V_e[t * 64 + s]; continue; }
    i -= 4096;
    if (i < 70144) { continue; }
    i -= 70144;
    if (i < 512) { ws[OFF_BENC + i] = bih_e[i] + bhh_e[i]; continue; }
    i -= 512;
    if (i < 32768) { continue; }
    i -= 32768;
    if (i < 135680) { continue; }
    i -= 135680;
    if (i < 512) { ws[OFF_BDEC + i] = bih_d[i] + bhh_d[i]; continue; }
    i -= 512;
    if (i < 768) { int k = i / 3, j = i % 3; ws[OFF_WOUTT + i] = W_out[j * 256 + k]; continue; }
  }
}

// ---------------------------------------------------------------- prep decoder MFMA weights
__global__ void prep_mfma_kernel(const float* __restrict__ W_d,
    const float* __restrict__ Wih_d, const float* __restrict__ Whh_d,
    unsigned short* __restrict__ WdTm, unsigned short* __restrict__ WdecTm) {
  int idx = blockIdx.x * blockDim.x + threadIdx.x;
  if (idx < 32768) {
    int j = idx & 7, l = (idx >> 3) & 63, t = idx >> 9;
    int nt = t & 7, ks = t >> 3;
    int k = ks * 32 + (l >> 4) * 8 + j;
    int n = nt * 16 + (l & 15);
    WdTm[idx] = f2bfu(W_d[n * 256 + k]);
    return;
  }
  int i2 = idx - 32768;
  if (i2 < 147456) {
    int j = i2 & 7, l = (i2 >> 3) & 63, t = i2 >> 9;
    int ks = t % 9, tile = t / 9;
    int q = tile & 3, is = tile >> 2;
    int k = ks * 32 + (l >> 4) * 8 + j;
    int g = q * 128 + is * 16 + (l & 15);
    float v;
    if (k < 128)      v = Whh_d[g * 128 + k];
    else if (k < 256) v = Wih_d[g * 137 + 9 + (k - 128)];
    else if (k < 265) v = Wih_d[g * 137 + (k - 256)];
    else              v = 0.f;
    WdecTm[i2] = f2bfu(v);
  }
}

// ---------------------------------------------------------------- prep encoder MFMA weights + VdTm
__global__ void prep_enc_mfma_kernel(const float* __restrict__ W_e,
    const float* __restrict__ Wih_e, const float* __restrict__ Whh_e,
    const float* __restrict__ V_d,
    unsigned short* __restrict__ WeTm, unsigned short* __restrict__ WencTm,
    unsigned short* __restrict__ VdTm) {
  int idx = blockIdx.x * blockDim.x + threadIdx.x;
  if (idx < 16384) {
    int j = idx & 7, l = (idx >> 3) & 63, tile = idx >> 9;
    int nt = tile & 3, ks = tile >> 2;
    int k = ks * 32 + (l >> 4) * 8 + j;
    int n = nt * 16 + (l & 15);
    WeTm[idx] = f2bfu(W_e[n * 256 + k]);
    return;
  }
  int i2 = idx - 16384;
  if (i2 < 81920) {
    int j = i2 & 7, l = (i2 >> 3) & 63, tile = i2 >> 9;
    int ks = tile % 5, tq = tile / 5;
    int q = tq & 3, is = tq >> 2;
    int kk = (l >> 4) * 8 + j;
    int g = q * 128 + is * 16 + (l & 15);
    float v;
    if (ks < 4) v = Whh_e[g * 128 + ks * 32 + kk];
    else        v = (kk < 9) ? Wih_e[g * 9 + kk] : 0.f;
    WencTm[i2] = f2bfu(v);
    return;
  }
  int i3 = i2 - 81920;
  if (i3 < 16384) {
    int j = i3 & 7, l = (i3 >> 3) & 63, tile = i3 >> 9;
    int nt = tile & 7, ks = tile >> 3;
    int i = ks * 32 + (l >> 4) * 8 + j;
    int n = nt * 16 + (l & 15);
    VdTm[i3] = f2bfu(V_d[n * 128 + i]);
  }
}

// ---------------------------------------------------------------- encoder (MFMA, 16 batches, 512 thr)
__global__ __launch_bounds__(512, 1) void encoder_mfma_kernel(
    const float* __restrict__ x_in, const float* __restrict__ ws,
    const float* __restrict__ v_e_g,
    const unsigned short* __restrict__ WeTm, const unsigned short* __restrict__ WencTm,
    __hip_bfloat16* __restrict__ EH,
    unsigned short* __restrict__ dG, float* __restrict__ cG) {
  __shared__ unsigned short hA[2][16 * 296];  // [h | c | xs | zeros]
  __shared__ float cF[16 * 132];
  __shared__ float ahL[16 * 64];
  __shared__ unsigned short aiL[16 * 576];    // bf16
  __shared__ unsigned short xbL[16 * 576];    // bf16

  const int tid = threadIdx.x;
  const int b0 = blockIdx.x * 16;
  const int l = tid & 63, w = tid >> 6;
  const int quad = l >> 4, l15 = l & 15;

  for (int i = tid; i < 16 * 576; i += 512) {
    int m = i / 576, r = i % 576;
    xbL[i] = f2bfu(x_in[(size_t)(b0 + m) * 576 + r]);
  }
  for (int i = tid; i < 2 * 16 * 296; i += 512) ((unsigned short*)hA)[i] = 0;
  for (int i = tid; i < 16 * 132; i += 512) cF[i] = 0.f;
  __syncthreads();

  {
    const float* __restrict__ VeT = ws + OFF_VET;
    for (int i = tid; i < 16 * 576; i += 512) {
      int t = i & 63, dd = (i >> 6) % 9, m = i / 576;
      float acc = 0.f;
      for (int s = 0; s < 64; ++s) acc += bfu2f(xbL[m * 576 + s * 9 + dd]) * VeT[s * 64 + t];
      aiL[m * 576 + dd * 64 + t] = f2bfu(acc);
    }
  }
  const float ve_r = v_e_g[l];
  const int ig = w * 16 + l15;
  float bbq[4];
  #pragma unroll
  for (int q = 0; q < 4; ++q) bbq[q] = ws[OFF_BENC + q * 128 + ig];
  __syncthreads();

  for (int t = 0; t < S_; ++t) {
    unsigned short* bufC = hA[t & 1];
    unsigned short* bufN = hA[(t + 1) & 1];
    if (w < 4) {
      f32x4 acc = {0.f, 0.f, 0.f, 0.f};
      #pragma unroll
      for (int ks = 0; ks < 8; ++ks) {
        uint4 au = *(const uint4*)&bufC[l15 * 296 + ks * 32 + quad * 8];
        uint4 bu = *(const uint4*)(WeTm + (size_t)((ks * 4 + w) * 64 + l) * 8);
        acc = __builtin_amdgcn_mfma_f32_16x16x32_bf16(
            __builtin_bit_cast(bf16x8, au), __builtin_bit_cast(bf16x8, bu), acc, 0, 0, 0);
      }
      #pragma unroll
      for (int r = 0; r < 4; ++r)
        ahL[(quad * 4 + r) * 64 + w * 16 + l15] = acc[r];
    }
    __syncthreads();
    {
      const int m0 = 2 * w, m1 = 2 * w + 1;
      float a0 = ahL[m0 * 64 + l], a1 = ahL[m1 * 64 + l];
      float e0k = -1e30f, e1k = -1e30f;
      #pragma unroll
      for (int dd = 0; dd < 9; ++dd) {
        float t0 = fast_tanh(a0 + bfu2f(aiL[m0 * 576 + dd * 64 + l])) * ve_r;
        float t1 = fast_tanh(a1 + bfu2f(aiL[m1 * 576 + dd * 64 + l])) * ve_r;
        #pragma unroll
        for (int off = 32; off; off >>= 1) {
          t0 += __shfl_xor(t0, off, 64);
          t1 += __shfl_xor(t1, off, 64);
        }
        if (l == dd) { e0k = t0; e1k = t1; }
      }
      float mx0 = e0k, mx1 = e1k;
      #pragma unroll
      for (int off = 8; off; off >>= 1) {
        mx0 = fmaxf(mx0, __shfl_xor(mx0, off, 64));
        mx1 = fmaxf(mx1, __shfl_xor(mx1, off, 64));
      }
      float ex0 = (l < 9) ? __expf(e0k - mx0) : 0.f;
      float ex1 = (l < 9) ? __expf(e1k - mx1) : 0.f;
      float s0 = ex0, s1 = ex1;
      #pragma unroll
      for (int off = 8; off; off >>= 1) {
        s0 += __shfl_xor(s0, off, 64);
        s1 += __shfl_xor(s1, off, 64);
      }
      if (l < 9) {
        bufC[m0 * 296 + 256 + l] = f2bfu(__fdividef(ex0, s0) * bfu2f(xbL[m0 * 576 + t * 9 + l]));
        bufC[m1 * 296 + 256 + l] = f2bfu(__fdividef(ex1, s1) * bfu2f(xbL[m1 * 576 + t * 9 + l]));
      }
    }
    __syncthreads();
    {
      uint4 af[5];
      #pragma unroll
      for (int ks = 0; ks < 4; ++ks)
        af[ks] = *(const uint4*)&bufC[l15 * 296 + ks * 32 + quad * 8];
      af[4] = *(const uint4*)&bufC[l15 * 296 + 256 + quad * 8];
      f32x4 g4[4];
      #pragma unroll
      for (int q = 0; q < 4; ++q) {
        f32x4 acc = {0.f, 0.f, 0.f, 0.f};
        #pragma unroll
        for (int ks = 0; ks < 5; ++ks) {
          uint4 bu = *(const uint4*)(WencTm + (size_t)(((w * 4 + q) * 5 + ks) * 64 + l) * 8);
          acc = __builtin_amdgcn_mfma_f32_16x16x32_bf16(
              __builtin_bit_cast(bf16x8, af[ks]), __builtin_bit_cast(bf16x8, bu), acc, 0, 0, 0);
        }
        g4[q] = acc;
      }
      #pragma unroll
      for (int r = 0; r < 4; ++r) {
        int m = quad * 4 + r;
        float gi = g4[0][r] + bbq[0];
        float gf = g4[1][r] + bbq[1];
        float gg = g4[2][r] + bbq[2];
        float go = g4[3][r] + bbq[3];
        float co = cF[m * 132 + ig];
        float cn = sigf(gf) * co + sigf(gi) * fast_tanh(gg);
        float hn = sigf(go) * fast_tanh(cn);
        cF[m * 132 + ig] = cn;
        bufN[m * 296 + ig] = f2bfu(hn);
        bufN[m * 296 + 128 + ig] = f2bfu(cn);
        EH[((size_t)(b0 + m) * S_ + t) * H_ + ig] = __float2bfloat16(hn);
      }
    }
    __syncthreads();
  }
  for (int i = tid; i < 16 * 128; i += 512) {
    int m = i >> 7, ii = i & 127;
    dG[(size_t)(b0 + m) * 128 + ii] = hA[0][m * 296 + ii];
    cG[(size_t)(b0 + m) * 128 + ii] = cF[m * 132 + ii];
  }
}

// ---------------------------------------------------------------- attn_encoder^T via MFMA -> fp8
__global__ __launch_bounds__(256) void attnenc_mfma_kernel(
    const unsigned short* __restrict__ EH, const unsigned short* __restrict__ VdTm,
    unsigned char* __restrict__ AETf8, unsigned char* __restrict__ EHf8) {
  const int tid = threadIdx.x;
  const int b = blockIdx.x * 4 + (tid >> 6);
  const int l = tid & 63;
  const int quad = l >> 4, l15 = l & 15;

  const unsigned short* ehb = EH + (size_t)b * 8192;
  uint4 A[4][4];
  #pragma unroll
  for (int st = 0; st < 4; ++st)
    #pragma unroll
    for (int ks = 0; ks < 4; ++ks)
      A[st][ks] = *(const uint4*)(ehb + (st * 16 + l15) * 128 + ks * 32 + quad * 8);

  {
    unsigned char* e8b = EHf8 + (size_t)b * 8192;
    #pragma unroll
    for (int st = 0; st < 4; ++st)
      #pragma unroll
      for (int ks = 0; ks < 4; ++ks) {
        uint4 a = A[st][ks];
        uint2 pk;
        pk.x = pack4_f8(bf_lo(a.x), bf_hi(a.x), bf_lo(a.y), bf_hi(a.y));
        pk.y = pack4_f8(bf_lo(a.z), bf_hi(a.z), bf_lo(a.w), bf_hi(a.w));
        *(uint2*)(e8b + (st * 16 + l15) * 128 + ks * 32 + quad * 8) = pk;
      }
  }

  unsigned char* outb = AETf8 + (size_t)b * 8192;
  const int k = l15;
  #pragma unroll
  for (int nt = 0; nt < 8; ++nt) {
    uint4 Bf[4];
    #pragma unroll
    for (int ks = 0; ks < 4; ++ks)
      Bf[ks] = *(const uint4*)(VdTm + (size_t)((ks * 8 + nt) * 64 + l) * 8);
    int kg = nt * 16 + k;
    int kb = kg >> 3, k7 = kg & 7;
    #pragma unroll
    for (int st = 0; st < 4; ++st) {
      f32x4 acc = {0.f, 0.f, 0.f, 0.f};
      #pragma unroll
      for (int ks = 0; ks < 4; ++ks)
        acc = __builtin_amdgcn_mfma_f32_16x16x32_bf16(
            __builtin_bit_cast(bf16x8, A[st][ks]), __builtin_bit_cast(bf16x8, Bf[ks]), acc, 0, 0, 0);
      #pragma unroll
      for (int r = 0; r < 4; ++r) {
        int s = st * 16 + quad * 4 + r;
        outb[kb * 512 + s * 8 + k7] = f2f8(acc[r]);
      }
    }
  }
}

// ---------------------------------------------------------------- fused persistent decoder v4
// 512 blocks x 512 threads (1/CU, 8 waves), 8 batches/block.
// ALL per-block activations (AETf8 + EHf8) live in LDS; weights (WdecTm 288K +
// WdTm 64K) are streamed from L2, where they are the ONLY recurring traffic per
// XCD (352 KB, permanently resident). No register-file weight residency -> no
// spills. Gates MFMA uses 16-row tiles with rows 8..15 zero-pad (MFMA is ~1%
// utilized; pad waste is free).
__global__ __launch_bounds__(512, 2) void dec_fused_kernel(
    const float* __restrict__ ws,
    const unsigned char* __restrict__ AETf8, const unsigned char* __restrict__ EHf8,
    const unsigned short* __restrict__ dG, const float* __restrict__ cG,
    const unsigned short* __restrict__ WdTm, const unsigned short* __restrict__ WdecTm,
    const float* __restrict__ v_d_g, const float* __restrict__ b_out_g,
    const float* __restrict__ smean_g, const float* __restrict__ sstd_g,
    const float* __restrict__ pmean_g,
    const float* __restrict__ x_in,
    float* __restrict__ out) {
  __shared__ unsigned char  AET[8][8192];   // 65536 B : staged AETf8 (kb*512 + s*8 + k7)
  __shared__ unsigned char  EHL[8][8192];   // 65536 B : staged EHf8 ([s][i] fp8)
  __shared__ unsigned short gA[16 * 296];   //  9472 B : gates A [d|ctx|phys|0], rows 8..15 pad
  __shared__ unsigned short dcB[16 * 264];  //  8448 B : ad-GEMM A [h|c], rows 8..15 pad
  __shared__ unsigned short adL[8 * 128];   //  2048 B : attn-hidden ad (bf16)
  __shared__ float          bet[8][64];     //  2048 B : beta
  __shared__ float          vdL[128];       //   512 B
  __shared__ float          pcs[8 * 3 * 8]; //   768 B : pred partials
  __shared__ float          pvs[8 * 12];    //   384 B : pos/vel/acc
  // total ~154.8 KB -> 1 block/CU (8 waves)

  const int tid = threadIdx.x;
  const int b0 = blockIdx.x * 8;
  const int l = tid & 63, w = tid >> 6;      // 8 waves
  const int quad = l >> 4, l15 = l & 15;
  const int i = w * 16 + l15;                // this thread's output column (0..127)

  // ---- one-time init: zero MFMA A-buffers (pad rows must be non-NaN)
  for (int idx = tid; idx < 16 * 296; idx += 512) gA[idx] = 0;
  for (int idx = tid; idx < 16 * 264; idx += 512) dcB[idx] = 0;
  // stage AETf8 + EHf8 (8 x 8 KB each)
  {
    const uint4* srcA = (const uint4*)(AETf8 + (size_t)b0 * 8192);
    const uint4* srcE = (const uint4*)(EHf8 + (size_t)b0 * 8192);
    uint4* dstA = (uint4*)AET;
    uint4* dstE = (uint4*)EHL;
    for (int idx = tid; idx < 4096; idx += 512) {
      dstA[idx] = srcA[idx];
      dstE[idx] = srcE[idx];
    }
  }
  if (tid < 128) vdL[tid] = v_d_g[tid];
  __syncthreads();

  // ---- load encoder final state into gA.d / dcB; phys init
  if (tid < 128) {
    int m = tid >> 4, i0 = (tid & 15) * 8;
    uint4 dv = *(const uint4*)(dG + (size_t)(b0 + m) * 128 + i0);
    *(uint4*)&gA[m * 296 + i0] = dv;
    *(uint4*)&dcB[m * 264 + i0] = dv;
    float4 c0 = *(const float4*)(cG + (size_t)(b0 + m) * 128 + i0);
    float4 c1 = *(const float4*)(cG + (size_t)(b0 + m) * 128 + i0 + 4);
    uint4 pk;
    pk.x = pack_bf(c0.x, c0.y); pk.y = pack_bf(c0.z, c0.w);
    pk.z = pack_bf(c1.x, c1.y); pk.w = pack_bf(c1.z, c1.w);
    *(uint4*)&dcB[m * 264 + 128 + i0] = pk;
  }
  if (tid < 24) {
    int m = tid / 3, jj = tid % 3;
    const float* xi = x_in + (size_t)(b0 + m) * 576;
    float sm = smean_g[jj], ss = sstd_g[jj], pm = pmean_g[jj];
    float v  = xi[63 * 9 + 3 + jj] * ss + sm;
    float pv = xi[62 * 9 + 3 + jj] * ss + sm;
    float pos = xi[63 * 9 + jj] + pm;
    float ac = (v - pv) / DT_;
    float* P = pvs + m * 12;
    P[jj] = pos; P[3 + jj] = v; P[6 + jj] = ac;
    gA[m * 296 + 256 + jj]     = f2bfu(pos - pm);
    gA[m * 296 + 256 + 3 + jj] = f2bfu((v - sm) / ss);
    gA[m * 296 + 256 + 6 + jj] = f2bfu(ac / ss);
  }
  // per-thread constants
  float bb[4];
  #pragma unroll
  for (int q = 0; q < 4; ++q) bb[q] = ws[OFF_BDEC + q * 128 + i];
  float k_sm = 0.f, k_ss = 1.f, k_pm = 0.f, k_bo = 0.f;
  if (tid < 24) {
    int jj = tid % 3;
    k_sm = smean_g[jj]; k_ss = sstd_g[jj]; k_pm = pmean_g[jj]; k_bo = b_out_g[jj];
  }
  // c-state in registers: quad<2 threads own rows m=quad*4+r (0..7) at column i
  float cReg[4];
  #pragma unroll
  for (int r = 0; r < 4; ++r)
    cReg[r] = (quad < 2) ? cG[(size_t)(b0 + quad * 4 + r) * 128 + i] : 0.f;
  __syncthreads();

  // ---- initial ad = [d|c] @ W_d^T
  {
    const int nt = w;
    f32x4 acc = {0.f, 0.f, 0.f, 0.f};
    #pragma unroll
    for (int ks = 0; ks < 8; ++ks) {
      uint4 au = *(const uint4*)&dcB[l15 * 264 + ks * 32 + quad * 8];
      uint4 bu = *(const uint4*)(WdTm + (size_t)((ks * 8 + nt) * 64 + l) * 8);
      acc = __builtin_amdgcn_mfma_f32_16x16x32_bf16(
          __builtin_bit_cast(bf16x8, au), __builtin_bit_cast(bf16x8, bu), acc, 0, 0, 0);
    }
    if (quad < 2) {
      int n = nt * 16 + l15;
      #pragma unroll
      for (int r = 0; r < 4; ++r) adL[(quad * 4 + r) * 128 + n] = f2bfu(acc[r]);
    }
  }
  __syncthreads();

  // ---- 32 decoder steps, fully in-kernel
  for (int hz = 0; hz < HZ_; ++hz) {
    // A: scores. wave w = batch w; lane = s; full k=128 per lane. AET from LDS.
    {
      const unsigned char* aet = AET[w];
      const unsigned short* adp = adL + w * 128;
      float e0 = 0.f;
      #pragma unroll
      for (int kb = 0; kb < 16; ++kb) {
        uint2 av = *(const uint2*)(aet + kb * 512 + l * 8);
        uint4 ad8 = *(const uint4*)(adp + kb * 8);
        float4 v0 = *(const float4*)&vdL[kb * 8];
        float4 v1 = *(const float4*)&vdL[kb * 8 + 4];
        f32x2 p0 = cvt2f8<false>(av.x), p1 = cvt2f8<true>(av.x);
        f32x2 p2 = cvt2f8<false>(av.y), p3 = cvt2f8<true>(av.y);
        e0 += fast_tanh(bf_lo(ad8.x) + p0[0]) * v0.x;
        e0 += fast_tanh(bf_hi(ad8.x) + p0[1]) * v0.y;
        e0 += fast_tanh(bf_lo(ad8.y) + p1[0]) * v0.z;
        e0 += fast_tanh(bf_hi(ad8.y) + p1[1]) * v0.w;
        e0 += fast_tanh(bf_lo(ad8.z) + p2[0]) * v1.x;
        e0 += fast_tanh(bf_hi(ad8.z) + p2[1]) * v1.y;
        e0 += fast_tanh(bf_lo(ad8.w) + p3[0]) * v1.z;
        e0 += fast_tanh(bf_hi(ad8.w) + p3[1]) * v1.w;
      }
      float mx = e0;
      #pragma unroll
      for (int off = 32; off; off >>= 1) mx = fmaxf(mx, __shfl_xor(mx, off, 64));
      float ex = __expf(e0 - mx);
      float ss = ex;
      #pragma unroll
      for (int off = 32; off; off >>= 1) ss += __shfl_xor(ss, off, 64);
      bet[w][l] = __fdividef(ex, ss);
    }
    // C: context = beta @ EH (fp8 from LDS, same-wave bet -> no barrier needed)
    {
      const unsigned char* ehb = EHL[w];
      const int i0 = l15 * 8;
      float a[8];
      #pragma unroll
      for (int r = 0; r < 8; ++r) a[r] = 0.f;
      #pragma unroll
      for (int it = 0; it < 16; ++it) {
        int s = quad * 16 + it;
        uint2 ev = *(const uint2*)(ehb + s * 128 + i0);
        float bt = bet[w][s];
        f32x2 c0 = cvt2f8<false>(ev.x), c1 = cvt2f8<true>(ev.x);
        f32x2 c2 = cvt2f8<false>(ev.y), c3 = cvt2f8<true>(ev.y);
        a[0] += bt * c0[0]; a[1] += bt * c0[1];
        a[2] += bt * c1[0]; a[3] += bt * c1[1];
        a[4] += bt * c2[0]; a[5] += bt * c2[1];
        a[6] += bt * c3[0]; a[7] += bt * c3[1];
      }
      #pragma unroll
      for (int r = 0; r < 8; ++r) {
        a[r] += __shfl_xor(a[r], 16, 64);
        a[r] += __shfl_xor(a[r], 32, 64);
      }
      if (quad == 0) {
        uint4 pk;
        pk.x = pack_bf(a[0], a[1]); pk.y = pack_bf(a[2], a[3]);
        pk.z = pack_bf(a[4], a[5]); pk.w = pack_bf(a[6], a[7]);
        *(uint4*)&gA[w * 296 + 128 + i0] = pk;
      }
    }
    __syncthreads();

    // E: preload gates A-frags (row l15 of [d|ctx|phys]) before G overwrites gA.d
    uint4 af[9];
    #pragma unroll
    for (int ks = 0; ks < 9; ++ks)
      af[ks] = *(const uint4*)&gA[l15 * 296 + ks * 32 + quad * 8];
    __syncthreads();

    // G: gates MFMA (B streamed from L2) + LSTM update (c in regs, rows 0..7 real)
    {
      f32x4 g4[4];
      #pragma unroll
      for (int q = 0; q < 4; ++q) {
        f32x4 acc = {0.f, 0.f, 0.f, 0.f};
        #pragma unroll
        for (int ks = 0; ks < 9; ++ks) {
          uint4 bu = *(const uint4*)(WdecTm + (size_t)(((w * 4 + q) * 9 + ks) * 64 + l) * 8);
          acc = __builtin_amdgcn_mfma_f32_16x16x32_bf16(
              __builtin_bit_cast(bf16x8, af[ks]), __builtin_bit_cast(bf16x8, bu), acc, 0, 0, 0);
        }
        g4[q] = acc;
      }
      if (quad < 2) {
        #pragma unroll
        for (int r = 0; r < 4; ++r) {
          int m = quad * 4 + r;
          float gi = g4[0][r] + bb[0];
          float gf = g4[1][r] + bb[1];
          float gg = g4[2][r] + bb[2];
          float go = g4[3][r] + bb[3];
          float cn = sigf(gf) * cReg[r] + sigf(gi) * fast_tanh(gg);
          float hn = sigf(go) * fast_tanh(cn);
          cReg[r] = cn;
          unsigned short hb = f2bfu(hn);
          gA[m * 296 + i] = hb;
          dcB[m * 264 + i] = hb;
          dcB[m * 264 + 128 + i] = f2bfu(cn);
        }
      }
    }
    __syncthreads();

    // I: next ad = [h|c] @ W_d^T (WdTm streamed from L2, 64 KB/block-step)
    {
      const int nt = w;
      f32x4 acc = {0.f, 0.f, 0.f, 0.f};
      #pragma unroll
      for (int ks = 0; ks < 8; ++ks) {
        uint4 au = *(const uint4*)&dcB[l15 * 264 + ks * 32 + quad * 8];
        uint4 bu = *(const uint4*)(WdTm + (size_t)((ks * 8 + nt) * 64 + l) * 8);
        acc = __builtin_amdgcn_mfma_f32_16x16x32_bf16(
            __builtin_bit_cast(bf16x8, au), __builtin_bit_cast(bf16x8, bu), acc, 0, 0, 0);
      }
      if (quad < 2) {
        int n = nt * 16 + l15;
        #pragma unroll
        for (int r = 0; r < 4; ++r) adL[(quad * 4 + r) * 128 + n] = f2bfu(acc[r]);
      }
    }
    // out-projection partials over [d_new | ctx] (reads gA, no conflict with I)
    if (tid < 192) {
      int m = tid / 24, r2 = tid % 24, jj = r2 >> 3, part = r2 & 7;
      float acc = 0.f;
      #pragma unroll 4
      for (int k = part * 32; k < part * 32 + 32; ++k)
        acc += bfu2f(gA[m * 296 + k]) * ws[OFF_WOUTT + k * 3 + jj];
      pcs[(m * 3 + jj) * 8 + part] = acc;
    }
    __syncthreads();

    // K: final pred + Verlet + output + next phys into gA.
    // No trailing barrier: K's writes (gA.phys, pvs) are disjoint from the next
    // step's A/C phases and ordered before all E-reads by the C barrier.
    if (tid < 24) {
      int m = tid / 3, jj = tid % 3;
      float s = k_bo;
      #pragma unroll
      for (int p = 0; p < 8; ++p) s += pcs[(m * 3 + jj) * 8 + p];
      float pacc = s * k_ss;
      float* P = pvs + m * 12;
      float pos = P[jj], vel = P[3 + jj], ac = P[6 + jj];
      float ppred = pos + vel * DT_ + 0.5f * ac * DT_ * DT_;
      float vnew  = vel + 0.5f * (ac + pacc) * DT_;
      size_t ob = ((size_t)(b0 + m) * HZ_ + hz) * 9;
      out[ob + jj] = ppred; out[ob + 3 + jj] = vnew; out[ob + 6 + jj] = pacc;
      P[jj] = ppred; P[3 + jj] = vnew; P[6 + jj] = pacc;
      gA[m * 296 + 256 + jj]     = f2bfu(ppred - k_pm);
      gA[m * 296 + 256 + 3 + jj] = f2bfu((vnew - k_sm) / k_ss);
      gA[m * 296 + 256 + 6 + jj] = f2bfu(pacc / k_ss);
    }
  }
}

// ---------------------------------------------------------------- launch
extern "C" void kernel_launch(void* const* d_in, const int* in_sizes, int n_in,
                              void* d_out, int out_size, void* d_ws, size_t ws_size,
                              hipStream_t stream) {
  (void)in_sizes; (void)n_in; (void)out_size; (void)ws_size;
  const float* x      = (const float*)d_in[0];
  const float* Wih_e  = (const float*)d_in[1];
  const float* Whh_e  = (const float*)d_in[2];
  const float* bih_e  = (const float*)d_in[3];
  const float* bhh_e  = (const float*)d_in[4];
  const float* W_e    = (const float*)d_in[5];
  const float* V_e    = (const float*)d_in[6];
  const float* v_e    = (const float*)d_in[7];
  const float* W_d    = (const float*)d_in[8];
  const float* V_d    = (const float*)d_in[9];
  const float* v_d    = (const float*)d_in[10];
  const float* Wih_d  = (const float*)d_in[11];
  const float* Whh_d  = (const float*)d_in[12];
  const float* bih_d  = (const float*)d_in[13];
  const float* bhh_d  = (const float*)d_in[14];
  const float* W_out  = (const float*)d_in[15];
  const float* b_out  = (const float*)d_in[16];
  const float* smean  = (const float*)d_in[17];
  const float* sstd   = (const float*)d_in[18];
  const float* pmean  = (const float*)d_in[19];

  float* ws = (float*)d_ws;
  unsigned short* WeTm   = (unsigned short*)(ws + OFF_WET);
  unsigned short* WencTm = (unsigned short*)(ws + OFF_WENCT);
  unsigned short* WdTm   = (unsigned short*)(ws + OFF_WDT);
  unsigned short* WdecTm = (unsigned short*)(ws + OFF_WDECT);
  unsigned short* VdTm   = (unsigned short*)(ws + OFF_VDT);
  unsigned short* dG     = (unsigned short*)(ws + OFF_DECD);
  float* cG = ws + OFF_DECC;
  unsigned short* ub  = (unsigned short*)(ws + F32_TOTAL);
  unsigned short* EH  = ub;
  unsigned char*  AETf8 = (unsigned char*)(ub + 33554432);     // 33.5 MB
  unsigned char*  EHf8  = AETf8 + (size_t)B_ * 8192;           // 33.5 MB
  float* out = (float*)d_out;

  prep_kernel<<<(PREP_N + 255) / 256, 256, 0, stream>>>(
      Wih_e, Whh_e, bih_e, bhh_e, W_e, V_e, W_d, V_d,
      Wih_d, Whh_d, bih_d, bhh_d, W_out, ws);
  prep_mfma_kernel<<<(32768 + 147456 + 255) / 256, 256, 0, stream>>>(
      W_d, Wih_d, Whh_d, WdTm, WdecTm);
  prep_enc_mfma_kernel<<<(16384 + 81920 + 16384 + 255) / 256, 256, 0, stream>>>(
      W_e, Wih_e, Whh_e, V_d, WeTm, WencTm, VdTm);
  encoder_mfma_kernel<<<B_ / 16, 512, 0, stream>>>(
      x, ws, v_e, WeTm, WencTm, (__hip_bfloat16*)EH, dG, cG);
  attnenc_mfma_kernel<<<B_ / 4, 256, 0, stream>>>(EH, VdTm, AETf8, EHf8);
  dec_fused_kernel<<<B_ / 8, 512, 0, stream>>>(
      ws, AETf8, EHf8, dG, cG, WdTm, WdecTm,
      v_d, b_out, smean, sstd, pmean, x, out);
}

// Round 6
// 1994.956 us; speedup vs baseline: 1.2265x; 1.0035x over previous
//
#include <hip/hip_runtime.h>
#include <hip/hip_bf16.h>
#include <hip/hip_fp8.h>

// Problem constants
#define B_   4096
#define S_   64
#define D_   9
#define H_   128
#define HZ_  32
#define DT_  0.1f

// f32 region layout (float offsets). Regions overlap in TIME, never within a kernel.
#define OFF_WET    0          // slot hosts WeTm  (bf16, 16384 ush) [encoder only]
#define OFF_VET    16384      // 4096 f32 V_e^T   [encoder only]
#define OFF_WENCT  20480      // slot hosts WencTm (bf16, 81920 ush) [encoder only]
#define OFF_BENC   90624      // 512   [encoder only]
#define OFF_WDT    91136      // slot hosts WdTm (bf16, 32768 ush)
#define OFF_WDECT  123904     // slot hosts WdecTm (bf16, 147456 ush)
#define OFF_BDEC   259584     // 512   (live, decoder)
#define OFF_WOUTT  260096     // 768   (live, decoder)
#define OFF_VDT    260864     // slot hosts VdTm (bf16, 16384 ush) [attnenc MFMA B-frags]
#define OFF_DECD   277248     // dG (524288 ush)
#define OFF_DECC   801536     // 524288 : cG f32
#define F32_TOTAL  1325824
#define PREP_N     277248

// dcx merged state buffer: [d0(128) | d1(128) | c(128) | ctx(128) | phys(9)+pad]
#define DCX_S   552   // row stride in ush; 276 dw = 20 mod 32 -> ~2-way a-frag reads
#define OF_D0   0
#define OF_D1   128
#define OF_C    256
#define OF_CTX  384
#define OF_PH   512

typedef __bf16 bf16x8 __attribute__((ext_vector_type(8)));
typedef float  f32x4  __attribute__((ext_vector_type(4)));
typedef float  f32x2  __attribute__((ext_vector_type(2)));

__device__ __forceinline__ float fast_tanh(float x) {
    float e = __expf(2.0f * x);
    return 1.0f - __fdividef(2.0f, e + 1.0f);
}
__device__ __forceinline__ float sigf(float x) {
    return __fdividef(1.0f, 1.0f + __expf(-x));
}
__device__ __forceinline__ float bf_lo(unsigned int u) { return __uint_as_float(u << 16); }
__device__ __forceinline__ float bf_hi(unsigned int u) { return __uint_as_float(u & 0xffff0000u); }
__device__ __forceinline__ float bfu2f(unsigned short u) { return __uint_as_float((unsigned int)u << 16); }
__device__ __forceinline__ unsigned short f2bfu(float f) {
    __hip_bfloat16 b = __float2bfloat16(f);
    return *(unsigned short*)&b;
}
__device__ __forceinline__ unsigned int pack_bf(float lo, float hi) {
    return (unsigned int)f2bfu(lo) | ((unsigned int)f2bfu(hi) << 16);
}
__device__ __forceinline__ float f8tof(unsigned int byte) {
    __hip_fp8_e4m3 t; t.__x = (unsigned char)byte; return (float)t;
}
__device__ __forceinline__ unsigned char f2f8(float f) {
    __hip_fp8_e4m3 q(f); return q.__x;
}
__device__ __forceinline__ unsigned int pack4_f8(float a, float b, float c, float d) {
    return (unsigned int)f2f8(a) | ((unsigned int)f2f8(b) << 8) |
           ((unsigned int)f2f8(c) << 16) | ((unsigned int)f2f8(d) << 24);
}
// native OCP-fp8 pair convert (gfx950): word-select must be a literal -> template param
template<bool HI>
__device__ __forceinline__ f32x2 cvt2f8(unsigned int u) {
    return __builtin_amdgcn_cvt_pk_f32_fp8(u, HI);
}

// ---------------------------------------------------------------- prep (f32 tables)
__global__ void prep_kernel(const float* __restrict__ Wih_e, const float* __restrict__ Whh_e,
    const float* __restrict__ bih_e, const float* __restrict__ bhh_e,
    const float* __restrict__ W_e, const float* __restrict__ V_e,
    const float* __restrict__ W_d, const float* __restrict__ V_d,
    const float* __restrict__ Wih_d, const float* __restrict__ Whh_d,
    const float* __restrict__ bih_d, const float* __restrict__ bhh_d,
    const float* __restrict__ W_out, float* __restrict__ ws) {
  for (int idx = blockIdx.x * blockDim.x + threadIdx.x; idx < PREP_N;
       idx += gridDim.x * blockDim.x) {
    int i = idx;
    if (i < 16384) { continue; }
    i -= 16384;
    if (i < 4096) { int s = i >> 6, t = i & 63; ws[OFF_VET + i] = V_e[t * 64 + s]; continue; }
    i -= 4096;
    if (i < 70144) { continue; }
    i -= 70144;
    if (i < 512) { ws[OFF_BENC + i] = bih_e[i] + bhh_e[i]; continue; }
    i -= 512;
    if (i < 32768) { continue; }
    i -= 32768;
    if (i < 135680) { continue; }
    i -= 135680;
    if (i < 512) { ws[OFF_BDEC + i] = bih_d[i] + bhh_d[i]; continue; }
    i -= 512;
    if (i < 768) { int k = i / 3, j = i % 3; ws[OFF_WOUTT + i] = W_out[j * 256 + k]; continue; }
  }
}

// ---------------------------------------------------------------- prep decoder MFMA weights
__global__ void prep_mfma_kernel(const float* __restrict__ W_d,
    const float* __restrict__ Wih_d, const float* __restrict__ Whh_d,
    unsigned short* __restrict__ WdTm, unsigned short* __restrict__ WdecTm) {
  int idx = blockIdx.x * blockDim.x + threadIdx.x;
  if (idx < 32768) {
    int j = idx & 7, l = (idx >> 3) & 63, t = idx >> 9;
    int nt = t & 7, ks = t >> 3;
    int k = ks * 32 + (l >> 4) * 8 + j;
    int n = nt * 16 + (l & 15);
    WdTm[idx] = f2bfu(W_d[n * 256 + k]);
    return;
  }
  int i2 = idx - 32768;
  if (i2 < 147456) {
    int j = i2 & 7, l = (i2 >> 3) & 63, t = i2 >> 9;
    int ks = t % 9, tile = t / 9;
    int q = tile & 3, is = tile >> 2;
    int k = ks * 32 + (l >> 4) * 8 + j;
    int g = q * 128 + is * 16 + (l & 15);
    float v;
    if (k < 128)      v = Whh_d[g * 128 + k];
    else if (k < 256) v = Wih_d[g * 137 + 9 + (k - 128)];
    else if (k < 265) v = Wih_d[g * 137 + (k - 256)];
    else              v = 0.f;
    WdecTm[i2] = f2bfu(v);
  }
}

// ---------------------------------------------------------------- prep encoder MFMA weights + VdTm
__global__ void prep_enc_mfma_kernel(const float* __restrict__ W_e,
    const float* __restrict__ Wih_e, const float* __restrict__ Whh_e,
    const float* __restrict__ V_d,
    unsigned short* __restrict__ WeTm, unsigned short* __restrict__ WencTm,
    unsigned short* __restrict__ VdTm) {
  int idx = blockIdx.x * blockDim.x + threadIdx.x;
  if (idx < 16384) {
    int j = idx & 7, l = (idx >> 3) & 63, tile = idx >> 9;
    int nt = tile & 3, ks = tile >> 2;
    int k = ks * 32 + (l >> 4) * 8 + j;
    int n = nt * 16 + (l & 15);
    WeTm[idx] = f2bfu(W_e[n * 256 + k]);
    return;
  }
  int i2 = idx - 16384;
  if (i2 < 81920) {
    int j = i2 & 7, l = (i2 >> 3) & 63, tile = i2 >> 9;
    int ks = tile % 5, tq = tile / 5;
    int q = tq & 3, is = tq >> 2;
    int kk = (l >> 4) * 8 + j;
    int g = q * 128 + is * 16 + (l & 15);
    float v;
    if (ks < 4) v = Whh_e[g * 128 + ks * 32 + kk];
    else        v = (kk < 9) ? Wih_e[g * 9 + kk] : 0.f;
    WencTm[i2] = f2bfu(v);
    return;
  }
  int i3 = i2 - 81920;
  if (i3 < 16384) {
    int j = i3 & 7, l = (i3 >> 3) & 63, tile = i3 >> 9;
    int nt = tile & 7, ks = tile >> 3;
    int i = ks * 32 + (l >> 4) * 8 + j;
    int n = nt * 16 + (l & 15);
    VdTm[i3] = f2bfu(V_d[n * 128 + i]);
  }
}

// ---------------------------------------------------------------- encoder (MFMA, 16 batches, 512 thr)
__global__ __launch_bounds__(512, 1) void encoder_mfma_kernel(
    const float* __restrict__ x_in, const float* __restrict__ ws,
    const float* __restrict__ v_e_g,
    const unsigned short* __restrict__ WeTm, const unsigned short* __restrict__ WencTm,
    __hip_bfloat16* __restrict__ EH,
    unsigned short* __restrict__ dG, float* __restrict__ cG) {
  __shared__ unsigned short hA[2][16 * 296];  // [h | c | xs | zeros]
  __shared__ float cF[16 * 132];
  __shared__ float ahL[16 * 64];
  __shared__ unsigned short aiL[16 * 576];    // bf16
  __shared__ unsigned short xbL[16 * 576];    // bf16

  const int tid = threadIdx.x;
  const int b0 = blockIdx.x * 16;
  const int l = tid & 63, w = tid >> 6;
  const int quad = l >> 4, l15 = l & 15;

  for (int i = tid; i < 16 * 576; i += 512) {
    int m = i / 576, r = i % 576;
    xbL[i] = f2bfu(x_in[(size_t)(b0 + m) * 576 + r]);
  }
  for (int i = tid; i < 2 * 16 * 296; i += 512) ((unsigned short*)hA)[i] = 0;
  for (int i = tid; i < 16 * 132; i += 512) cF[i] = 0.f;
  __syncthreads();

  {
    const float* __restrict__ VeT = ws + OFF_VET;
    for (int i = tid; i < 16 * 576; i += 512) {
      int t = i & 63, dd = (i >> 6) % 9, m = i / 576;
      float acc = 0.f;
      for (int s = 0; s < 64; ++s) acc += bfu2f(xbL[m * 576 + s * 9 + dd]) * VeT[s * 64 + t];
      aiL[m * 576 + dd * 64 + t] = f2bfu(acc);
    }
  }
  const float ve_r = v_e_g[l];
  const int ig = w * 16 + l15;
  float bbq[4];
  #pragma unroll
  for (int q = 0; q < 4; ++q) bbq[q] = ws[OFF_BENC + q * 128 + ig];
  __syncthreads();

  for (int t = 0; t < S_; ++t) {
    unsigned short* bufC = hA[t & 1];
    unsigned short* bufN = hA[(t + 1) & 1];
    if (w < 4) {
      f32x4 acc = {0.f, 0.f, 0.f, 0.f};
      #pragma unroll
      for (int ks = 0; ks < 8; ++ks) {
        uint4 au = *(const uint4*)&bufC[l15 * 296 + ks * 32 + quad * 8];
        uint4 bu = *(const uint4*)(WeTm + (size_t)((ks * 4 + w) * 64 + l) * 8);
        acc = __builtin_amdgcn_mfma_f32_16x16x32_bf16(
            __builtin_bit_cast(bf16x8, au), __builtin_bit_cast(bf16x8, bu), acc, 0, 0, 0);
      }
      #pragma unroll
      for (int r = 0; r < 4; ++r)
        ahL[(quad * 4 + r) * 64 + w * 16 + l15] = acc[r];
    }
    __syncthreads();
    {
      const int m0 = 2 * w, m1 = 2 * w + 1;
      float a0 = ahL[m0 * 64 + l], a1 = ahL[m1 * 64 + l];
      float e0k = -1e30f, e1k = -1e30f;
      #pragma unroll
      for (int dd = 0; dd < 9; ++dd) {
        float t0 = fast_tanh(a0 + bfu2f(aiL[m0 * 576 + dd * 64 + l])) * ve_r;
        float t1 = fast_tanh(a1 + bfu2f(aiL[m1 * 576 + dd * 64 + l])) * ve_r;
        #pragma unroll
        for (int off = 32; off; off >>= 1) {
          t0 += __shfl_xor(t0, off, 64);
          t1 += __shfl_xor(t1, off, 64);
        }
        if (l == dd) { e0k = t0; e1k = t1; }
      }
      float mx0 = e0k, mx1 = e1k;
      #pragma unroll
      for (int off = 8; off; off >>= 1) {
        mx0 = fmaxf(mx0, __shfl_xor(mx0, off, 64));
        mx1 = fmaxf(mx1, __shfl_xor(mx1, off, 64));
      }
      float ex0 = (l < 9) ? __expf(e0k - mx0) : 0.f;
      float ex1 = (l < 9) ? __expf(e1k - mx1) : 0.f;
      float s0 = ex0, s1 = ex1;
      #pragma unroll
      for (int off = 8; off; off >>= 1) {
        s0 += __shfl_xor(s0, off, 64);
        s1 += __shfl_xor(s1, off, 64);
      }
      if (l < 9) {
        bufC[m0 * 296 + 256 + l] = f2bfu(__fdividef(ex0, s0) * bfu2f(xbL[m0 * 576 + t * 9 + l]));
        bufC[m1 * 296 + 256 + l] = f2bfu(__fdividef(ex1, s1) * bfu2f(xbL[m1 * 576 + t * 9 + l]));
      }
    }
    __syncthreads();
    {
      uint4 af[5];
      #pragma unroll
      for (int ks = 0; ks < 4; ++ks)
        af[ks] = *(const uint4*)&bufC[l15 * 296 + ks * 32 + quad * 8];
      af[4] = *(const uint4*)&bufC[l15 * 296 + 256 + quad * 8];
      f32x4 g4[4];
      #pragma unroll
      for (int q = 0; q < 4; ++q) {
        f32x4 acc = {0.f, 0.f, 0.f, 0.f};
        #pragma unroll
        for (int ks = 0; ks < 5; ++ks) {
          uint4 bu = *(const uint4*)(WencTm + (size_t)(((w * 4 + q) * 5 + ks) * 64 + l) * 8);
          acc = __builtin_amdgcn_mfma_f32_16x16x32_bf16(
              __builtin_bit_cast(bf16x8, af[ks]), __builtin_bit_cast(bf16x8, bu), acc, 0, 0, 0);
        }
        g4[q] = acc;
      }
      #pragma unroll
      for (int r = 0; r < 4; ++r) {
        int m = quad * 4 + r;
        float gi = g4[0][r] + bbq[0];
        float gf = g4[1][r] + bbq[1];
        float gg = g4[2][r] + bbq[2];
        float go = g4[3][r] + bbq[3];
        float co = cF[m * 132 + ig];
        float cn = sigf(gf) * co + sigf(gi) * fast_tanh(gg);
        float hn = sigf(go) * fast_tanh(cn);
        cF[m * 132 + ig] = cn;
        bufN[m * 296 + ig] = f2bfu(hn);
        bufN[m * 296 + 128 + ig] = f2bfu(cn);
        EH[((size_t)(b0 + m) * S_ + t) * H_ + ig] = __float2bfloat16(hn);
      }
    }
    __syncthreads();
  }
  for (int i = tid; i < 16 * 128; i += 512) {
    int m = i >> 7, ii = i & 127;
    dG[(size_t)(b0 + m) * 128 + ii] = hA[0][m * 296 + ii];
    cG[(size_t)(b0 + m) * 128 + ii] = cF[m * 132 + ii];
  }
}

// ---------------------------------------------------------------- attn_encoder^T via MFMA -> fp8
__global__ __launch_bounds__(256) void attnenc_mfma_kernel(
    const unsigned short* __restrict__ EH, const unsigned short* __restrict__ VdTm,
    unsigned char* __restrict__ AETf8, unsigned char* __restrict__ EHf8) {
  const int tid = threadIdx.x;
  const int b = blockIdx.x * 4 + (tid >> 6);
  const int l = tid & 63;
  const int quad = l >> 4, l15 = l & 15;

  const unsigned short* ehb = EH + (size_t)b * 8192;
  uint4 A[4][4];
  #pragma unroll
  for (int st = 0; st < 4; ++st)
    #pragma unroll
    for (int ks = 0; ks < 4; ++ks)
      A[st][ks] = *(const uint4*)(ehb + (st * 16 + l15) * 128 + ks * 32 + quad * 8);

  {
    unsigned char* e8b = EHf8 + (size_t)b * 8192;
    #pragma unroll
    for (int st = 0; st < 4; ++st)
      #pragma unroll
      for (int ks = 0; ks < 4; ++ks) {
        uint4 a = A[st][ks];
        uint2 pk;
        pk.x = pack4_f8(bf_lo(a.x), bf_hi(a.x), bf_lo(a.y), bf_hi(a.y));
        pk.y = pack4_f8(bf_lo(a.z), bf_hi(a.z), bf_lo(a.w), bf_hi(a.w));
        *(uint2*)(e8b + (st * 16 + l15) * 128 + ks * 32 + quad * 8) = pk;
      }
  }

  unsigned char* outb = AETf8 + (size_t)b * 8192;
  const int k = l15;
  #pragma unroll
  for (int nt = 0; nt < 8; ++nt) {
    uint4 Bf[4];
    #pragma unroll
    for (int ks = 0; ks < 4; ++ks)
      Bf[ks] = *(const uint4*)(VdTm + (size_t)((ks * 8 + nt) * 64 + l) * 8);
    int kg = nt * 16 + k;
    int kb = kg >> 3, k7 = kg & 7;
    #pragma unroll
    for (int st = 0; st < 4; ++st) {
      f32x4 acc = {0.f, 0.f, 0.f, 0.f};
      #pragma unroll
      for (int ks = 0; ks < 4; ++ks)
        acc = __builtin_amdgcn_mfma_f32_16x16x32_bf16(
            __builtin_bit_cast(bf16x8, A[st][ks]), __builtin_bit_cast(bf16x8, Bf[ks]), acc, 0, 0, 0);
      #pragma unroll
      for (int r = 0; r < 4; ++r) {
        int s = st * 16 + quad * 4 + r;
        outb[kb * 512 + s * 8 + k7] = f2f8(acc[r]);
      }
    }
  }
}

// ---------------------------------------------------------------- fused persistent decoder v5
// 512 blocks x 512 threads (1/CU, 8 waves), 8 batches/block.
// Activations (AETf8 + EHf8) in LDS; weights streamed from L2.
// d-region DOUBLE-BUFFERED in merged state buffer dcx -> no G-phase read/write race
// -> no af[] preload, no E phase, 3 barriers/step, low VGPR pressure (no spills).
__global__ __launch_bounds__(512, 2) void dec_fused_kernel(
    const float* __restrict__ ws,
    const unsigned char* __restrict__ AETf8, const unsigned char* __restrict__ EHf8,
    const unsigned short* __restrict__ dG, const float* __restrict__ cG,
    const unsigned short* __restrict__ WdTm, const unsigned short* __restrict__ WdecTm,
    const float* __restrict__ v_d_g, const float* __restrict__ b_out_g,
    const float* __restrict__ smean_g, const float* __restrict__ sstd_g,
    const float* __restrict__ pmean_g,
    const float* __restrict__ x_in,
    float* __restrict__ out) {
  __shared__ unsigned char  AET[8][8192];     // 65536 B
  __shared__ unsigned char  EHL[8][8192];     // 65536 B
  __shared__ unsigned short dcx[16 * DCX_S];  // 17664 B : [d0|d1|c|ctx|phys], rows 8..15 pad
  __shared__ unsigned short adL[8 * 128];     //  2048 B
  __shared__ float          bet[8][64];       //  2048 B
  __shared__ float          vdL[128];         //   512 B
  __shared__ float          pcs[8 * 3 * 8];   //   768 B
  __shared__ float          pvs[8 * 12];      //   384 B
  // total ~154.5 KB -> 1 block/CU (8 waves)

  const int tid = threadIdx.x;
  const int b0 = blockIdx.x * 8;
  const int l = tid & 63, w = tid >> 6;      // 8 waves
  const int quad = l >> 4, l15 = l & 15;
  const int i = w * 16 + l15;                // this thread's output column (0..127)

  // ---- one-time init: zero dcx (pad rows/cols must be non-NaN)
  for (int idx = tid; idx < 16 * DCX_S; idx += 512) dcx[idx] = 0;
  // stage AETf8 + EHf8 (8 x 8 KB each)
  {
    const uint4* srcA = (const uint4*)(AETf8 + (size_t)b0 * 8192);
    const uint4* srcE = (const uint4*)(EHf8 + (size_t)b0 * 8192);
    uint4* dstA = (uint4*)AET;
    uint4* dstE = (uint4*)EHL;
    for (int idx = tid; idx < 4096; idx += 512) {
      dstA[idx] = srcA[idx];
      dstE[idx] = srcE[idx];
    }
  }
  if (tid < 128) vdL[tid] = v_d_g[tid];
  __syncthreads();

  // ---- load encoder final state into dcx.d0 / dcx.c; phys init
  if (tid < 128) {
    int m = tid >> 4, i0 = (tid & 15) * 8;
    uint4 dv = *(const uint4*)(dG + (size_t)(b0 + m) * 128 + i0);
    *(uint4*)&dcx[m * DCX_S + OF_D0 + i0] = dv;
    float4 c0 = *(const float4*)(cG + (size_t)(b0 + m) * 128 + i0);
    float4 c1 = *(const float4*)(cG + (size_t)(b0 + m) * 128 + i0 + 4);
    uint4 pk;
    pk.x = pack_bf(c0.x, c0.y); pk.y = pack_bf(c0.z, c0.w);
    pk.z = pack_bf(c1.x, c1.y); pk.w = pack_bf(c1.z, c1.w);
    *(uint4*)&dcx[m * DCX_S + OF_C + i0] = pk;
  }
  if (tid < 24) {
    int m = tid / 3, jj = tid % 3;
    const float* xi = x_in + (size_t)(b0 + m) * 576;
    float sm = smean_g[jj], ss = sstd_g[jj], pm = pmean_g[jj];
    float v  = xi[63 * 9 + 3 + jj] * ss + sm;
    float pv = xi[62 * 9 + 3 + jj] * ss + sm;
    float pos = xi[63 * 9 + jj] + pm;
    float ac = (v - pv) / DT_;
    float* P = pvs + m * 12;
    P[jj] = pos; P[3 + jj] = v; P[6 + jj] = ac;
    dcx[m * DCX_S + OF_PH + jj]     = f2bfu(pos - pm);
    dcx[m * DCX_S + OF_PH + 3 + jj] = f2bfu((v - sm) / ss);
    dcx[m * DCX_S + OF_PH + 6 + jj] = f2bfu(ac / ss);
  }
  // per-thread constants
  float bb[4];
  #pragma unroll
  for (int q = 0; q < 4; ++q) bb[q] = ws[OFF_BDEC + q * 128 + i];
  float k_sm = 0.f, k_ss = 1.f, k_pm = 0.f, k_bo = 0.f;
  if (tid < 24) {
    int jj = tid % 3;
    k_sm = smean_g[jj]; k_ss = sstd_g[jj]; k_pm = pmean_g[jj]; k_bo = b_out_g[jj];
  }
  // c-state in registers: quad<2 threads own rows m=quad*4+r (0..7) at column i
  float cReg[4];
  #pragma unroll
  for (int r = 0; r < 4; ++r)
    cReg[r] = (quad < 2) ? cG[(size_t)(b0 + quad * 4 + r) * 128 + i] : 0.f;
  __syncthreads();

  // ---- initial ad = [d0|c] @ W_d^T
  {
    const int nt = w;
    f32x4 acc = {0.f, 0.f, 0.f, 0.f};
    #pragma unroll
    for (int ks = 0; ks < 8; ++ks) {
      int off = (ks < 4) ? (OF_D0 + ks * 32) : (OF_C + (ks - 4) * 32);
      uint4 au = *(const uint4*)&dcx[l15 * DCX_S + off + quad * 8];
      uint4 bu = *(const uint4*)(WdTm + (size_t)((ks * 8 + nt) * 64 + l) * 8);
      acc = __builtin_amdgcn_mfma_f32_16x16x32_bf16(
          __builtin_bit_cast(bf16x8, au), __builtin_bit_cast(bf16x8, bu), acc, 0, 0, 0);
    }
    if (quad < 2) {
      int n = nt * 16 + l15;
      #pragma unroll
      for (int r = 0; r < 4; ++r) adL[(quad * 4 + r) * 128 + n] = f2bfu(acc[r]);
    }
  }
  __syncthreads();

  // ---- 32 decoder steps, fully in-kernel
  for (int hz = 0; hz < HZ_; ++hz) {
    const int dcur = (hz & 1) ? OF_D1 : OF_D0;   // d read by gates this step
    const int dnxt = (hz & 1) ? OF_D0 : OF_D1;   // h written this step

    // A: scores. wave w = batch w; lane = s; full k=128 per lane; 4 acc chains.
    {
      const unsigned char* aet = AET[w];
      const unsigned short* adp = adL + w * 128;
      float eacc[4] = {0.f, 0.f, 0.f, 0.f};
      #pragma unroll
      for (int kb = 0; kb < 16; ++kb) {
        uint2 av = *(const uint2*)(aet + kb * 512 + l * 8);
        uint4 ad8 = *(const uint4*)(adp + kb * 8);
        float4 v0 = *(const float4*)&vdL[kb * 8];
        float4 v1 = *(const float4*)&vdL[kb * 8 + 4];
        f32x2 p0 = cvt2f8<false>(av.x), p1 = cvt2f8<true>(av.x);
        f32x2 p2 = cvt2f8<false>(av.y), p3 = cvt2f8<true>(av.y);
        float e = eacc[kb & 3];
        e += fast_tanh(bf_lo(ad8.x) + p0[0]) * v0.x;
        e += fast_tanh(bf_hi(ad8.x) + p0[1]) * v0.y;
        e += fast_tanh(bf_lo(ad8.y) + p1[0]) * v0.z;
        e += fast_tanh(bf_hi(ad8.y) + p1[1]) * v0.w;
        e += fast_tanh(bf_lo(ad8.z) + p2[0]) * v1.x;
        e += fast_tanh(bf_hi(ad8.z) + p2[1]) * v1.y;
        e += fast_tanh(bf_lo(ad8.w) + p3[0]) * v1.z;
        e += fast_tanh(bf_hi(ad8.w) + p3[1]) * v1.w;
        eacc[kb & 3] = e;
      }
      float e0 = (eacc[0] + eacc[1]) + (eacc[2] + eacc[3]);
      float mx = e0;
      #pragma unroll
      for (int off = 32; off; off >>= 1) mx = fmaxf(mx, __shfl_xor(mx, off, 64));
      float ex = __expf(e0 - mx);
      float ss = ex;
      #pragma unroll
      for (int off = 32; off; off >>= 1) ss += __shfl_xor(ss, off, 64);
      bet[w][l] = __fdividef(ex, ss);
    }
    // C: context = beta @ EH (fp8 from LDS, same-wave bet -> no barrier needed)
    {
      const unsigned char* ehb = EHL[w];
      const int i0 = l15 * 8;
      float a[8];
      #pragma unroll
      for (int r = 0; r < 8; ++r) a[r] = 0.f;
      #pragma unroll
      for (int it = 0; it < 16; ++it) {
        int s = quad * 16 + it;
        uint2 ev = *(const uint2*)(ehb + s * 128 + i0);
        float bt = bet[w][s];
        f32x2 c0 = cvt2f8<false>(ev.x), c1 = cvt2f8<true>(ev.x);
        f32x2 c2 = cvt2f8<false>(ev.y), c3 = cvt2f8<true>(ev.y);
        a[0] += bt * c0[0]; a[1] += bt * c0[1];
        a[2] += bt * c1[0]; a[3] += bt * c1[1];
        a[4] += bt * c2[0]; a[5] += bt * c2[1];
        a[6] += bt * c3[0]; a[7] += bt * c3[1];
      }
      #pragma unroll
      for (int r = 0; r < 8; ++r) {
        a[r] += __shfl_xor(a[r], 16, 64);
        a[r] += __shfl_xor(a[r], 32, 64);
      }
      if (quad == 0) {
        uint4 pk;
        pk.x = pack_bf(a[0], a[1]); pk.y = pack_bf(a[2], a[3]);
        pk.z = pack_bf(a[4], a[5]); pk.w = pack_bf(a[6], a[7]);
        *(uint4*)&dcx[w * DCX_S + OF_CTX + i0] = pk;
      }
    }
    __syncthreads();

    // G: gates MFMA reads [d_cur | ctx | phys], writes h -> d_nxt, c -> c.
    // No race: read and write regions are disjoint (double-buffered d).
    {
      f32x4 g4[4];
      #pragma unroll
      for (int q = 0; q < 4; ++q) g4[q] = (f32x4){0.f, 0.f, 0.f, 0.f};
      #pragma unroll
      for (int ks = 0; ks < 9; ++ks) {
        int off = (ks < 4) ? (dcur + ks * 32)
                           : ((ks < 8) ? (OF_CTX + (ks - 4) * 32) : OF_PH);
        uint4 af = *(const uint4*)&dcx[l15 * DCX_S + off + quad * 8];
        #pragma unroll
        for (int q = 0; q < 4; ++q) {
          uint4 bu = *(const uint4*)(WdecTm + (size_t)(((w * 4 + q) * 9 + ks) * 64 + l) * 8);
          g4[q] = __builtin_amdgcn_mfma_f32_16x16x32_bf16(
              __builtin_bit_cast(bf16x8, af), __builtin_bit_cast(bf16x8, bu), g4[q], 0, 0, 0);
        }
      }
      if (quad < 2) {
        #pragma unroll
        for (int r = 0; r < 4; ++r) {
          int m = quad * 4 + r;
          float gi = g4[0][r] + bb[0];
          float gf = g4[1][r] + bb[1];
          float gg = g4[2][r] + bb[2];
          float go = g4[3][r] + bb[3];
          float cn = sigf(gf) * cReg[r] + sigf(gi) * fast_tanh(gg);
          float hn = sigf(go) * fast_tanh(cn);
          cReg[r] = cn;
          dcx[m * DCX_S + dnxt + i] = f2bfu(hn);
          dcx[m * DCX_S + OF_C + i] = f2bfu(cn);
        }
      }
    }
    __syncthreads();

    // I: next ad = [h|c] @ W_d^T (h = d_nxt region)
    {
      const int nt = w;
      f32x4 acc = {0.f, 0.f, 0.f, 0.f};
      #pragma unroll
      for (int ks = 0; ks < 8; ++ks) {
        int off = (ks < 4) ? (dnxt + ks * 32) : (OF_C + (ks - 4) * 32);
        uint4 au = *(const uint4*)&dcx[l15 * DCX_S + off + quad * 8];
        uint4 bu = *(const uint4*)(WdTm + (size_t)((ks * 8 + nt) * 64 + l) * 8);
        acc = __builtin_amdgcn_mfma_f32_16x16x32_bf16(
            __builtin_bit_cast(bf16x8, au), __builtin_bit_cast(bf16x8, bu), acc, 0, 0, 0);
      }
      if (quad < 2) {
        int n = nt * 16 + l15;
        #pragma unroll
        for (int r = 0; r < 4; ++r) adL[(quad * 4 + r) * 128 + n] = f2bfu(acc[r]);
      }
    }
    // out-projection partials over [d_nxt | ctx]
    if (tid < 192) {
      int m = tid / 24, r2 = tid % 24, jj = r2 >> 3, part = r2 & 7;
      int kbase = (part < 4) ? (dnxt + part * 32) : (OF_CTX + (part - 4) * 32);
      float acc = 0.f;
      #pragma unroll 4
      for (int kk = 0; kk < 32; ++kk)
        acc += bfu2f(dcx[m * DCX_S + kbase + kk]) * ws[OFF_WOUTT + (part * 32 + kk) * 3 + jj];
      pcs[(m * 3 + jj) * 8 + part] = acc;
    }
    __syncthreads();

    // K: final pred + Verlet + output + next phys into dcx.
    // No trailing barrier: K's writes (dcx.phys, pvs) are disjoint from the next
    // step's A/C phases and ordered before all G-reads by the C barrier.
    if (tid < 24) {
      int m = tid / 3, jj = tid % 3;
      float s = k_bo;
      #pragma unroll
      for (int p = 0; p < 8; ++p) s += pcs[(m * 3 + jj) * 8 + p];
      float pacc = s * k_ss;
      float* P = pvs + m * 12;
      float pos = P[jj], vel = P[3 + jj], ac = P[6 + jj];
      float ppred = pos + vel * DT_ + 0.5f * ac * DT_ * DT_;
      float vnew  = vel + 0.5f * (ac + pacc) * DT_;
      size_t ob = ((size_t)(b0 + m) * HZ_ + hz) * 9;
      out[ob + jj] = ppred; out[ob + 3 + jj] = vnew; out[ob + 6 + jj] = pacc;
      P[jj] = ppred; P[3 + jj] = vnew; P[6 + jj] = pacc;
      dcx[m * DCX_S + OF_PH + jj]     = f2bfu(ppred - k_pm);
      dcx[m * DCX_S + OF_PH + 3 + jj] = f2bfu((vnew - k_sm) / k_ss);
      dcx[m * DCX_S + OF_PH + 6 + jj] = f2bfu(pacc / k_ss);
    }
  }
}

// ---------------------------------------------------------------- launch
extern "C" void kernel_launch(void* const* d_in, const int* in_sizes, int n_in,
                              void* d_out, int out_size, void* d_ws, size_t ws_size,
                              hipStream_t stream) {
  (void)in_sizes; (void)n_in; (void)out_size; (void)ws_size;
  const float* x      = (const float*)d_in[0];
  const float* Wih_e  = (const float*)d_in[1];
  const float* Whh_e  = (const float*)d_in[2];
  const float* bih_e  = (const float*)d_in[3];
  const float* bhh_e  = (const float*)d_in[4];
  const float* W_e    = (const float*)d_in[5];
  const float* V_e    = (const float*)d_in[6];
  const float* v_e    = (const float*)d_in[7];
  const float* W_d    = (const float*)d_in[8];
  const float* V_d    = (const float*)d_in[9];
  const float* v_d    = (const float*)d_in[10];
  const float* Wih_d  = (const float*)d_in[11];
  const float* Whh_d  = (const float*)d_in[12];
  const float* bih_d  = (const float*)d_in[13];
  const float* bhh_d  = (const float*)d_in[14];
  const float* W_out  = (const float*)d_in[15];
  const float* b_out  = (const float*)d_in[16];
  const float* smean  = (const float*)d_in[17];
  const float* sstd   = (const float*)d_in[18];
  const float* pmean  = (const float*)d_in[19];

  float* ws = (float*)d_ws;
  unsigned short* WeTm   = (unsigned short*)(ws + OFF_WET);
  unsigned short* WencTm = (unsigned short*)(ws + OFF_WENCT);
  unsigned short* WdTm   = (unsigned short*)(ws + OFF_WDT);
  unsigned short* WdecTm = (unsigned short*)(ws + OFF_WDECT);
  unsigned short* VdTm   = (unsigned short*)(ws + OFF_VDT);
  unsigned short* dG     = (unsigned short*)(ws + OFF_DECD);
  float* cG = ws + OFF_DECC;
  unsigned short* ub  = (unsigned short*)(ws + F32_TOTAL);
  unsigned short* EH  = ub;
  unsigned char*  AETf8 = (unsigned char*)(ub + 33554432);     // 33.5 MB
  unsigned char*  EHf8  = AETf8 + (size_t)B_ * 8192;           // 33.5 MB
  float* out = (float*)d_out;

  prep_kernel<<<(PREP_N + 255) / 256, 256, 0, stream>>>(
      Wih_e, Whh_e, bih_e, bhh_e, W_e, V_e, W_d, V_d,
      Wih_d, Whh_d, bih_d, bhh_d, W_out, ws);
  prep_mfma_kernel<<<(32768 + 147456 + 255) / 256, 256, 0, stream>>>(
      W_d, Wih_d, Whh_d, WdTm, WdecTm);
  prep_enc_mfma_kernel<<<(16384 + 81920 + 16384 + 255) / 256, 256, 0, stream>>>(
      W_e, Wih_e, Whh_e, V_d, WeTm, WencTm, VdTm);
  encoder_mfma_kernel<<<B_ / 16, 512, 0, stream>>>(
      x, ws, v_e, WeTm, WencTm, (__hip_bfloat16*)EH, dG, cG);
  attnenc_mfma_kernel<<<B_ / 4, 256, 0, stream>>>(EH, VdTm, AETf8, EHf8);
  dec_fused_kernel<<<B_ / 8, 512, 0, stream>>>(
      ws, AETf8, EHf8, dG, cG, WdTm, WdecTm,
      v_d, b_out, smean, sstd, pmean, x, out);
}